// Round 4
// baseline (276.935 us; speedup 1.0000x reference)
//
#include <hip/hip_runtime.h>
#include <hip/hip_bf16.h>

namespace {
constexpr int kB   = 4;
constexpr int kL   = 2048;
constexpr int kLc  = 2051;   // L + 3
constexpr int kD   = 1024;
constexpr int kS   = 64;
constexpr int kM   = kB * kLc;  // 8204 flattened (b,t) rows
constexpr int kNR  = 256;       // raw row stride (196 real cols, padded)
constexpr int kQ   = 64;        // scan time-chunk length
constexpr int kTC  = (kLc + kQ - 1) / kQ;  // 33 chunks per batch
}

__device__ __forceinline__ float siluf_(float v) {
  return v / (1.f + expf(-v));
}
__device__ __forceinline__ float softplusf_(float v) {
  return (v > 20.f) ? v : log1pf(expf(v));
}

// ---------------- K1: depthwise conv1d, pad=3, KW=4 -> xc [B, Lc, D] ------
__global__ __launch_bounds__(256) void conv_kernel(
    const float* __restrict__ x, const float* __restrict__ cw,
    const float* __restrict__ cb, float* __restrict__ xc) {
  int idx = blockIdx.x * blockDim.x + threadIdx.x;
  const int D4 = kD / 4;
  if (idx >= kB * kLc * D4) return;
  int d4 = idx % D4;
  int bt = idx / D4;
  int t = bt % kLc;
  int b = bt / kLc;
  int d = d4 * 4;

  float4 w0 = *(const float4*)(cw + (size_t)(d + 0) * 4);
  float4 w1 = *(const float4*)(cw + (size_t)(d + 1) * 4);
  float4 w2 = *(const float4*)(cw + (size_t)(d + 2) * 4);
  float4 w3 = *(const float4*)(cw + (size_t)(d + 3) * 4);
  float4 acc = *(const float4*)(cb + d);

#pragma unroll
  for (int k = 0; k < 4; ++k) {
    int ti = t + k - 3;
    if (ti >= 0 && ti < kL) {
      float4 xv = *(const float4*)(x + ((size_t)b * kL + ti) * kD + d);
      acc.x = fmaf(((const float*)&w0)[k], xv.x, acc.x);
      acc.y = fmaf(((const float*)&w1)[k], xv.y, acc.y);
      acc.z = fmaf(((const float*)&w2)[k], xv.z, acc.z);
      acc.w = fmaf(((const float*)&w3)[k], xv.w, acc.w);
    }
  }
  *(float4*)(xc + (size_t)bt * kD + d) = acc;
}

// ---------------- K2a: raw = xc @ Wcat^T  (fp32 tiled GEMM) ---------------
__global__ __launch_bounds__(256) void gemm_kernel(
    const float* __restrict__ xc,
    const float* __restrict__ W_U, const float* __restrict__ W_B,
    const float* __restrict__ W_C, const float* __restrict__ W_d1,
    float* __restrict__ raw) {
  __shared__ __align__(16) float xcl[32][68];
  __shared__ __align__(16) float wl[32][68];

  const int tid = threadIdx.x;
  const int m0 = blockIdx.x * 64;
  const int n0 = blockIdx.y * 64;
  const int tm = tid >> 4;
  const int tn = tid & 15;
  const int sm = tid >> 3;
  const int skq = tid & 7;

  const float* wsrc[2];
  bool wval[2];
#pragma unroll
  for (int p = 0; p < 2; ++p) {
    int col = n0 + sm + p * 32;
    const float* src = nullptr;
    if (col < 64)       src = W_U + (size_t)col * kD;
    else if (col < 128) src = W_B + (size_t)(col - 64) * kD;
    else if (col < 192) src = W_C + (size_t)(col - 128) * kD;
    else if (col < 196) src = W_d1 + (size_t)(col - 192) * kD;
    wsrc[p] = src;
    wval[p] = (src != nullptr);
  }
  const float* xsrc[2];
  bool xval[2];
#pragma unroll
  for (int p = 0; p < 2; ++p) {
    int row = m0 + sm + p * 32;
    xval[p] = (row < kM);
    xsrc[p] = xc + (size_t)row * kD;
  }

  float acc[4][4];
#pragma unroll
  for (int i = 0; i < 4; ++i)
#pragma unroll
    for (int j = 0; j < 4; ++j) acc[i][j] = 0.f;

  for (int kb = 0; kb < kD; kb += 32) {
    __syncthreads();
#pragma unroll
    for (int p = 0; p < 2; ++p) {
      int m = sm + p * 32;
      float4 xv = make_float4(0.f, 0.f, 0.f, 0.f);
      float4 wv = make_float4(0.f, 0.f, 0.f, 0.f);
      if (xval[p]) xv = *(const float4*)(xsrc[p] + kb + skq * 4);
      if (wval[p]) wv = *(const float4*)(wsrc[p] + kb + skq * 4);
      xcl[skq * 4 + 0][m] = xv.x;
      xcl[skq * 4 + 1][m] = xv.y;
      xcl[skq * 4 + 2][m] = xv.z;
      xcl[skq * 4 + 3][m] = xv.w;
      wl[skq * 4 + 0][m] = wv.x;
      wl[skq * 4 + 1][m] = wv.y;
      wl[skq * 4 + 2][m] = wv.z;
      wl[skq * 4 + 3][m] = wv.w;
    }
    __syncthreads();
#pragma unroll
    for (int k = 0; k < 32; ++k) {
      float4 a = *(const float4*)&xcl[k][tm * 4];
      float4 w = *(const float4*)&wl[k][tn * 4];
      const float* ap = (const float*)&a;
      const float* wp = (const float*)&w;
#pragma unroll
      for (int i = 0; i < 4; ++i)
#pragma unroll
        for (int j = 0; j < 4; ++j) acc[i][j] = fmaf(ap[i], wp[j], acc[i][j]);
    }
  }

#pragma unroll
  for (int i = 0; i < 4; ++i) {
    int row = m0 + tm * 4 + i;
    if (row < kM) {
      *(float4*)(raw + (size_t)row * kNR + n0 + tn * 4) =
          make_float4(acc[i][0], acc[i][1], acc[i][2], acc[i][3]);
    }
  }
}

// ---------------- K2b: epilogue -> At, Bt, Ct ----------------------------
__global__ __launch_bounds__(256) void epi_kernel(
    const float* __restrict__ raw,
    const float* __restrict__ b_B, const float* __restrict__ b_C,
    const float* __restrict__ b_d1, const float* __restrict__ W_d2,
    const float* __restrict__ b_d2, const float* __restrict__ a_hat,
    float* __restrict__ At, float* __restrict__ Bt, float* __restrict__ Ct) {
  int idx = blockIdx.x * blockDim.x + threadIdx.x;
  if (idx >= kM * kS) return;
  int s = idx & 63;
  int row = idx >> 6;
  const float* r = raw + (size_t)row * kNR;

  float u  = r[s];
  float rb = r[64 + s] + b_B[s];
  float rc = r[128 + s] + b_C[s];
  float f0 = siluf_(r[192] + b_d1[0]);
  float f1 = siluf_(r[193] + b_d1[1]);
  float f2 = siluf_(r[194] + b_d1[2]);
  float f3 = siluf_(r[195] + b_d1[3]);
  float z = fmaf(f0, W_d2[0], fmaf(f1, W_d2[1], fmaf(f2, W_d2[2], fmaf(f3, W_d2[3], b_d2[0]))));
  float delta = softplusf_(z);
  size_t o = (size_t)row * kS + s;
  At[o] = expf(delta * -expf(a_hat[s]));
  Bt[o] = rb * u;
  Ct[o] = rc;
}

// ---------------- K3a: per-chunk backward cumprod -------------------------
__global__ __launch_bounds__(64) void prep_kernel(
    const float* __restrict__ At, const float* __restrict__ Bt,
    float* __restrict__ Bpre, float* __restrict__ dec) {
  __shared__ __align__(16) float Aloc[kQ][kS];
  __shared__ __align__(16) float Bloc[kQ][kS];
  int tid = threadIdx.x;  // 64
  int bc = blockIdx.x;
  int b = bc / kTC, c = bc % kTC;
  int t0 = c * kQ;
  int clen = min(kQ, kLc - t0);
  size_t baseS = ((size_t)b * kLc + t0) * kS;

  for (int i = tid; i < kQ * (kS / 4); i += 64) {
    int tt = i >> 4;
    int sq = i & 15;
    float4 a = make_float4(1.f, 1.f, 1.f, 1.f);
    float4 bv = make_float4(0.f, 0.f, 0.f, 0.f);
    if (tt < clen) {
      a  = *(const float4*)(At + baseS + (size_t)tt * kS + sq * 4);
      bv = *(const float4*)(Bt + baseS + (size_t)tt * kS + sq * 4);
    }
    *(float4*)&Aloc[tt][sq * 4] = a;
    *(float4*)&Bloc[tt][sq * 4] = bv;
  }
  __syncthreads();
  int s = tid;
  float E = 1.f;
  for (int tt = kQ - 1; tt >= 0; --tt) {
    Bpre[((size_t)bc * kQ + tt) * kS + s] = E * Bloc[tt][s];
    E *= Aloc[tt][s];
  }
  dec[(size_t)bc * kS + s] = E;
}

// ---------------- K3b: partial end-state GEMM -----------------------------
__global__ __launch_bounds__(256) void pstate_kernel(
    const float* __restrict__ Bpre, const float* __restrict__ xc,
    float* __restrict__ Sc) {
  __shared__ __align__(16) float bpl[16][68];
  __shared__ __align__(16) float xl[16][68];
  int tid = threadIdx.x;
  int bc = blockIdx.y;
  int b = bc / kTC, c = bc % kTC;
  int d0 = blockIdx.x * 64;
  int tm = tid >> 4, tn = tid & 15;
  int srow = tid >> 4, scol = tid & 15;
  int t0 = c * kQ;

  float acc[4][4];
#pragma unroll
  for (int i = 0; i < 4; ++i)
#pragma unroll
    for (int j = 0; j < 4; ++j) acc[i][j] = 0.f;

  for (int kb = 0; kb < kQ; kb += 16) {
    __syncthreads();
    {
      float4 bv = *(const float4*)(Bpre + ((size_t)bc * kQ + kb + srow) * kS + scol * 4);
      int gt = t0 + kb + srow;
      if (gt > kLc - 1) gt = kLc - 1;  // clamp; Bpre is 0 there
      float4 xv = *(const float4*)(xc + ((size_t)b * kLc + gt) * kD + d0 + scol * 4);
      *(float4*)&bpl[srow][scol * 4] = bv;
      *(float4*)&xl[srow][scol * 4] = xv;
    }
    __syncthreads();
#pragma unroll
    for (int k = 0; k < 16; ++k) {
      float4 a = *(const float4*)&bpl[k][tm * 4];
      float4 w = *(const float4*)&xl[k][tn * 4];
      const float* ap = (const float*)&a;
      const float* wp = (const float*)&w;
#pragma unroll
      for (int i = 0; i < 4; ++i)
#pragma unroll
        for (int j = 0; j < 4; ++j) acc[i][j] = fmaf(ap[i], wp[j], acc[i][j]);
    }
  }
#pragma unroll
  for (int i = 0; i < 4; ++i) {
    *(float4*)(Sc + ((size_t)bc * kS + tm * 4 + i) * kD + d0 + tn * 4) =
        make_float4(acc[i][0], acc[i][1], acc[i][2], acc[i][3]);
  }
}

// ---------------- K3c: cross-chunk state scan (in-place Sc -> H_before) ---
__global__ __launch_bounds__(256) void chscan_kernel(
    const float* __restrict__ dec, float* __restrict__ Sc) {
  int bs = blockIdx.x;           // b*kS + s
  int dq = threadIdx.x;          // 0..255 -> d quad
  int b = bs >> 6, s = bs & 63;
  float4 run = make_float4(0.f, 0.f, 0.f, 0.f);
  for (int c = 0; c < kTC; ++c) {
    size_t off = ((size_t)(b * kTC + c) * kS + s) * kD + dq * 4;
    float4 tmp = *(const float4*)(Sc + off);
    *(float4*)(Sc + off) = run;  // H_before[c]
    float dc = dec[(size_t)(b * kTC + c) * kS + s];
    run.x = fmaf(dc, run.x, tmp.x);
    run.y = fmaf(dc, run.y, tmp.y);
    run.z = fmaf(dc, run.z, tmp.z);
    run.w = fmaf(dc, run.w, tmp.w);
  }
}

// ---------------- K3d: final chunked scan (thread = d-channel) ------------
// block = (bc, 128-channel group); h[64] in VGPRs; A/B/C LDS-broadcast.
__global__ __launch_bounds__(128) void final_kernel(
    const float* __restrict__ At, const float* __restrict__ Bt,
    const float* __restrict__ Ct, const float* __restrict__ xc,
    const float* __restrict__ Hst, const float* __restrict__ D_skip,
    float* __restrict__ out) {
  __shared__ __align__(16) float Al[16][kS];
  __shared__ __align__(16) float Bl[16][kS];
  __shared__ __align__(16) float Cl[16][kS];
  __shared__ __align__(16) float xcl[16][128];

  int tid = threadIdx.x;          // 0..127
  int bc = blockIdx.x >> 3;       // b*kTC + c
  int d0 = (blockIdx.x & 7) << 7; // 0,128,...,896
  int b = bc / kTC, c = bc % kTC;
  int t0 = c * kQ;
  int clen = min(kQ, kLc - t0);
  int d = d0 + tid;

  float h[kS];
  {
    size_t hb = (size_t)bc * kS * kD + d;
#pragma unroll
    for (int s = 0; s < kS; ++s) h[s] = Hst[hb + (size_t)s * kD];
  }
  float ds = D_skip[d];
  size_t baseS = ((size_t)b * kLc + t0) * kS;
  size_t baseD = ((size_t)b * kLc + t0) * kD;

  for (int tile = 0; tile < kQ; tile += 16) {
    int sl = min(16, clen - tile);
    if (sl <= 0) break;
    __syncthreads();
    // stage A/B/C [sl][64]
    for (int i = tid; i < sl * 16; i += 128) {
      int tt = i >> 4, sq = i & 15;
      size_t g = baseS + (size_t)(tile + tt) * kS + sq * 4;
      *(float4*)&Al[tt][sq * 4] = *(const float4*)(At + g);
      *(float4*)&Bl[tt][sq * 4] = *(const float4*)(Bt + g);
      *(float4*)&Cl[tt][sq * 4] = *(const float4*)(Ct + g);
    }
    // stage xc [sl][128]
    for (int i = tid; i < sl * 32; i += 128) {
      int tt = i >> 5, dq = i & 31;
      *(float4*)&xcl[tt][dq * 4] =
          *(const float4*)(xc + baseD + (size_t)(tile + tt) * kD + d0 + dq * 4);
    }
    __syncthreads();

    for (int tt = 0; tt < sl; ++tt) {
      float xcv = xcl[tt][tid];
      float dot0 = 0.f, dot1 = 0.f, dot2 = 0.f, dot3 = 0.f;
#pragma unroll
      for (int s4 = 0; s4 < 16; ++s4) {
        float4 a = *(const float4*)&Al[tt][s4 * 4];
        float4 bv = *(const float4*)&Bl[tt][s4 * 4];
        float4 cv = *(const float4*)&Cl[tt][s4 * 4];
        h[s4 * 4 + 0] = fmaf(a.x, h[s4 * 4 + 0], bv.x * xcv);
        h[s4 * 4 + 1] = fmaf(a.y, h[s4 * 4 + 1], bv.y * xcv);
        h[s4 * 4 + 2] = fmaf(a.z, h[s4 * 4 + 2], bv.z * xcv);
        h[s4 * 4 + 3] = fmaf(a.w, h[s4 * 4 + 3], bv.w * xcv);
        dot0 = fmaf(cv.x, h[s4 * 4 + 0], dot0);
        dot1 = fmaf(cv.y, h[s4 * 4 + 1], dot1);
        dot2 = fmaf(cv.z, h[s4 * 4 + 2], dot2);
        dot3 = fmaf(cv.w, h[s4 * 4 + 3], dot3);
      }
      out[baseD + (size_t)(tile + tt) * kD + d] =
          fmaf(ds, xcv, (dot0 + dot1) + (dot2 + dot3));
    }
  }
}

extern "C" void kernel_launch(void* const* d_in, const int* in_sizes, int n_in,
                              void* d_out, int out_size, void* d_ws, size_t ws_size,
                              hipStream_t stream) {
  const float* x      = (const float*)d_in[0];
  const float* a_hat  = (const float*)d_in[1];
  const float* W_U    = (const float*)d_in[2];
  const float* W_B    = (const float*)d_in[3];
  const float* b_B    = (const float*)d_in[4];
  const float* W_C    = (const float*)d_in[5];
  const float* b_C    = (const float*)d_in[6];
  const float* W_d1   = (const float*)d_in[7];
  const float* b_d1   = (const float*)d_in[8];
  const float* W_d2   = (const float*)d_in[9];
  const float* b_d2   = (const float*)d_in[10];
  const float* D_skip = (const float*)d_in[11];
  const float* conv_w = (const float*)d_in[12];
  const float* conv_b = (const float*)d_in[13];
  float* out = (float*)d_out;

  float* xc   = (float*)d_ws;                        // kM*kD
  float* raw  = xc + (size_t)kM * kD;                // kM*kNR
  float* At   = raw + (size_t)kM * kNR;              // kM*kS
  float* Bt   = At + (size_t)kM * kS;
  float* Ct   = Bt + (size_t)kM * kS;
  float* Bpre = Ct + (size_t)kM * kS;                // B*TC*Q*S
  float* dec  = Bpre + (size_t)kB * kTC * kQ * kS;   // B*TC*S
  float* Sc   = dec + (size_t)kB * kTC * kS;         // B*TC*S*D (becomes H)

  int convThreads = kB * kLc * (kD / 4);
  conv_kernel<<<(convThreads + 255) / 256, 256, 0, stream>>>(x, conv_w, conv_b, xc);

  dim3 ggrid((kM + 63) / 64, 4);
  gemm_kernel<<<ggrid, 256, 0, stream>>>(xc, W_U, W_B, W_C, W_d1, raw);

  epi_kernel<<<(kM * kS + 255) / 256, 256, 0, stream>>>(
      raw, b_B, b_C, b_d1, W_d2, b_d2, a_hat, At, Bt, Ct);

  prep_kernel<<<kB * kTC, 64, 0, stream>>>(At, Bt, Bpre, dec);

  dim3 pgrid(kD / 64, kB * kTC);
  pstate_kernel<<<pgrid, 256, 0, stream>>>(Bpre, xc, Sc);

  chscan_kernel<<<kB * kS, kD / 4, 0, stream>>>(dec, Sc);

  final_kernel<<<kB * kTC * 8, 128, 0, stream>>>(
      At, Bt, Ct, xc, Sc, D_skip, out);
}

// Round 5
// 275.116 us; speedup vs baseline: 1.0066x; 1.0066x over previous
//
#include <hip/hip_runtime.h>
#include <hip/hip_bf16.h>

namespace {
constexpr int kB   = 4;
constexpr int kL   = 2048;
constexpr int kLc  = 2051;   // L + 3
constexpr int kD   = 1024;
constexpr int kS   = 64;
constexpr int kM   = kB * kLc;  // 8204 flattened (b,t) rows
constexpr int kNR  = 256;       // raw row stride (196 real cols, padded)
constexpr int kQ   = 64;        // scan time-chunk length
constexpr int kTC  = (kLc + kQ - 1) / kQ;  // 33 chunks per batch
}

__device__ __forceinline__ float siluf_(float v) {
  return v / (1.f + expf(-v));
}
__device__ __forceinline__ float softplusf_(float v) {
  return (v > 20.f) ? v : log1pf(expf(v));
}

// ---------------- K1: depthwise conv1d, pad=3, KW=4 -> xc [B, Lc, D] ------
__global__ __launch_bounds__(256) void conv_kernel(
    const float* __restrict__ x, const float* __restrict__ cw,
    const float* __restrict__ cb, float* __restrict__ xc) {
  int idx = blockIdx.x * blockDim.x + threadIdx.x;
  const int D4 = kD / 4;
  if (idx >= kB * kLc * D4) return;
  int d4 = idx % D4;
  int bt = idx / D4;
  int t = bt % kLc;
  int b = bt / kLc;
  int d = d4 * 4;

  float4 w0 = *(const float4*)(cw + (size_t)(d + 0) * 4);
  float4 w1 = *(const float4*)(cw + (size_t)(d + 1) * 4);
  float4 w2 = *(const float4*)(cw + (size_t)(d + 2) * 4);
  float4 w3 = *(const float4*)(cw + (size_t)(d + 3) * 4);
  float4 acc = *(const float4*)(cb + d);

#pragma unroll
  for (int k = 0; k < 4; ++k) {
    int ti = t + k - 3;
    if (ti >= 0 && ti < kL) {
      float4 xv = *(const float4*)(x + ((size_t)b * kL + ti) * kD + d);
      acc.x = fmaf(((const float*)&w0)[k], xv.x, acc.x);
      acc.y = fmaf(((const float*)&w1)[k], xv.y, acc.y);
      acc.z = fmaf(((const float*)&w2)[k], xv.z, acc.z);
      acc.w = fmaf(((const float*)&w3)[k], xv.w, acc.w);
    }
  }
  *(float4*)(xc + (size_t)bt * kD + d) = acc;
}

// ---------------- K2a: raw = xc @ Wcat^T  (fp32 tiled GEMM) ---------------
__global__ __launch_bounds__(256) void gemm_kernel(
    const float* __restrict__ xc,
    const float* __restrict__ W_U, const float* __restrict__ W_B,
    const float* __restrict__ W_C, const float* __restrict__ W_d1,
    float* __restrict__ raw) {
  __shared__ __align__(16) float xcl[32][68];
  __shared__ __align__(16) float wl[32][68];

  const int tid = threadIdx.x;
  const int m0 = blockIdx.x * 64;
  const int n0 = blockIdx.y * 64;
  const int tm = tid >> 4;
  const int tn = tid & 15;
  const int sm = tid >> 3;
  const int skq = tid & 7;

  const float* wsrc[2];
  bool wval[2];
#pragma unroll
  for (int p = 0; p < 2; ++p) {
    int col = n0 + sm + p * 32;
    const float* src = nullptr;
    if (col < 64)       src = W_U + (size_t)col * kD;
    else if (col < 128) src = W_B + (size_t)(col - 64) * kD;
    else if (col < 192) src = W_C + (size_t)(col - 128) * kD;
    else if (col < 196) src = W_d1 + (size_t)(col - 192) * kD;
    wsrc[p] = src;
    wval[p] = (src != nullptr);
  }
  const float* xsrc[2];
  bool xval[2];
#pragma unroll
  for (int p = 0; p < 2; ++p) {
    int row = m0 + sm + p * 32;
    xval[p] = (row < kM);
    xsrc[p] = xc + (size_t)row * kD;
  }

  float acc[4][4];
#pragma unroll
  for (int i = 0; i < 4; ++i)
#pragma unroll
    for (int j = 0; j < 4; ++j) acc[i][j] = 0.f;

  for (int kb = 0; kb < kD; kb += 32) {
    __syncthreads();
#pragma unroll
    for (int p = 0; p < 2; ++p) {
      int m = sm + p * 32;
      float4 xv = make_float4(0.f, 0.f, 0.f, 0.f);
      float4 wv = make_float4(0.f, 0.f, 0.f, 0.f);
      if (xval[p]) xv = *(const float4*)(xsrc[p] + kb + skq * 4);
      if (wval[p]) wv = *(const float4*)(wsrc[p] + kb + skq * 4);
      xcl[skq * 4 + 0][m] = xv.x;
      xcl[skq * 4 + 1][m] = xv.y;
      xcl[skq * 4 + 2][m] = xv.z;
      xcl[skq * 4 + 3][m] = xv.w;
      wl[skq * 4 + 0][m] = wv.x;
      wl[skq * 4 + 1][m] = wv.y;
      wl[skq * 4 + 2][m] = wv.z;
      wl[skq * 4 + 3][m] = wv.w;
    }
    __syncthreads();
#pragma unroll
    for (int k = 0; k < 32; ++k) {
      float4 a = *(const float4*)&xcl[k][tm * 4];
      float4 w = *(const float4*)&wl[k][tn * 4];
      const float* ap = (const float*)&a;
      const float* wp = (const float*)&w;
#pragma unroll
      for (int i = 0; i < 4; ++i)
#pragma unroll
        for (int j = 0; j < 4; ++j) acc[i][j] = fmaf(ap[i], wp[j], acc[i][j]);
    }
  }

#pragma unroll
  for (int i = 0; i < 4; ++i) {
    int row = m0 + tm * 4 + i;
    if (row < kM) {
      *(float4*)(raw + (size_t)row * kNR + n0 + tn * 4) =
          make_float4(acc[i][0], acc[i][1], acc[i][2], acc[i][3]);
    }
  }
}

// ---------------- K2b: epilogue -> At, Bt, Ct ----------------------------
__global__ __launch_bounds__(256) void epi_kernel(
    const float* __restrict__ raw,
    const float* __restrict__ b_B, const float* __restrict__ b_C,
    const float* __restrict__ b_d1, const float* __restrict__ W_d2,
    const float* __restrict__ b_d2, const float* __restrict__ a_hat,
    float* __restrict__ At, float* __restrict__ Bt, float* __restrict__ Ct) {
  int idx = blockIdx.x * blockDim.x + threadIdx.x;
  if (idx >= kM * kS) return;
  int s = idx & 63;
  int row = idx >> 6;
  const float* r = raw + (size_t)row * kNR;

  float u  = r[s];
  float rb = r[64 + s] + b_B[s];
  float rc = r[128 + s] + b_C[s];
  float f0 = siluf_(r[192] + b_d1[0]);
  float f1 = siluf_(r[193] + b_d1[1]);
  float f2 = siluf_(r[194] + b_d1[2]);
  float f3 = siluf_(r[195] + b_d1[3]);
  float z = fmaf(f0, W_d2[0], fmaf(f1, W_d2[1], fmaf(f2, W_d2[2], fmaf(f3, W_d2[3], b_d2[0]))));
  float delta = softplusf_(z);
  size_t o = (size_t)row * kS + s;
  At[o] = expf(delta * -expf(a_hat[s]));
  Bt[o] = rb * u;
  Ct[o] = rc;
}

// ---------------- K3a: per-chunk backward cumprod -------------------------
__global__ __launch_bounds__(64) void prep_kernel(
    const float* __restrict__ At, const float* __restrict__ Bt,
    float* __restrict__ Bpre, float* __restrict__ dec) {
  __shared__ __align__(16) float Aloc[kQ][kS];
  __shared__ __align__(16) float Bloc[kQ][kS];
  int tid = threadIdx.x;  // 64
  int bc = blockIdx.x;
  int b = bc / kTC, c = bc % kTC;
  int t0 = c * kQ;
  int clen = min(kQ, kLc - t0);
  size_t baseS = ((size_t)b * kLc + t0) * kS;

  for (int i = tid; i < kQ * (kS / 4); i += 64) {
    int tt = i >> 4;
    int sq = i & 15;
    float4 a = make_float4(1.f, 1.f, 1.f, 1.f);
    float4 bv = make_float4(0.f, 0.f, 0.f, 0.f);
    if (tt < clen) {
      a  = *(const float4*)(At + baseS + (size_t)tt * kS + sq * 4);
      bv = *(const float4*)(Bt + baseS + (size_t)tt * kS + sq * 4);
    }
    *(float4*)&Aloc[tt][sq * 4] = a;
    *(float4*)&Bloc[tt][sq * 4] = bv;
  }
  __syncthreads();
  int s = tid;
  float E = 1.f;
  for (int tt = kQ - 1; tt >= 0; --tt) {
    Bpre[((size_t)bc * kQ + tt) * kS + s] = E * Bloc[tt][s];
    E *= Aloc[tt][s];
  }
  dec[(size_t)bc * kS + s] = E;
}

// ---------------- K3b: partial end-state GEMM -----------------------------
__global__ __launch_bounds__(256) void pstate_kernel(
    const float* __restrict__ Bpre, const float* __restrict__ xc,
    float* __restrict__ Sc) {
  __shared__ __align__(16) float bpl[16][68];
  __shared__ __align__(16) float xl[16][68];
  int tid = threadIdx.x;
  int bc = blockIdx.y;
  int b = bc / kTC, c = bc % kTC;
  int d0 = blockIdx.x * 64;
  int tm = tid >> 4, tn = tid & 15;
  int srow = tid >> 4, scol = tid & 15;
  int t0 = c * kQ;

  float acc[4][4];
#pragma unroll
  for (int i = 0; i < 4; ++i)
#pragma unroll
    for (int j = 0; j < 4; ++j) acc[i][j] = 0.f;

  for (int kb = 0; kb < kQ; kb += 16) {
    __syncthreads();
    {
      float4 bv = *(const float4*)(Bpre + ((size_t)bc * kQ + kb + srow) * kS + scol * 4);
      int gt = t0 + kb + srow;
      if (gt > kLc - 1) gt = kLc - 1;  // clamp; Bpre is 0 there
      float4 xv = *(const float4*)(xc + ((size_t)b * kLc + gt) * kD + d0 + scol * 4);
      *(float4*)&bpl[srow][scol * 4] = bv;
      *(float4*)&xl[srow][scol * 4] = xv;
    }
    __syncthreads();
#pragma unroll
    for (int k = 0; k < 16; ++k) {
      float4 a = *(const float4*)&bpl[k][tm * 4];
      float4 w = *(const float4*)&xl[k][tn * 4];
      const float* ap = (const float*)&a;
      const float* wp = (const float*)&w;
#pragma unroll
      for (int i = 0; i < 4; ++i)
#pragma unroll
        for (int j = 0; j < 4; ++j) acc[i][j] = fmaf(ap[i], wp[j], acc[i][j]);
    }
  }
#pragma unroll
  for (int i = 0; i < 4; ++i) {
    *(float4*)(Sc + ((size_t)bc * kS + tm * 4 + i) * kD + d0 + tn * 4) =
        make_float4(acc[i][0], acc[i][1], acc[i][2], acc[i][3]);
  }
}

// ---------------- K3c: cross-chunk state scan (in-place Sc -> H_before) ---
__global__ __launch_bounds__(256) void chscan_kernel(
    const float* __restrict__ dec, float* __restrict__ Sc) {
  int bs = blockIdx.x;           // b*kS + s
  int dq = threadIdx.x;          // 0..255 -> d quad
  int b = bs >> 6, s = bs & 63;
  float4 run = make_float4(0.f, 0.f, 0.f, 0.f);
  for (int c = 0; c < kTC; ++c) {
    size_t off = ((size_t)(b * kTC + c) * kS + s) * kD + dq * 4;
    float4 tmp = *(const float4*)(Sc + off);
    *(float4*)(Sc + off) = run;  // H_before[c]
    float dc = dec[(size_t)(b * kTC + c) * kS + s];
    run.x = fmaf(dc, run.x, tmp.x);
    run.y = fmaf(dc, run.y, tmp.y);
    run.z = fmaf(dc, run.z, tmp.z);
    run.w = fmaf(dc, run.w, tmp.w);
  }
}

// ---------------- K3d: final chunked scan (V=4 d/thread, s-split-2) -------
// block = (bc, half of d); 4 waves; lane = (dl 0..31, sh = s-half).
// Each thread: h[4][32] regs = 4 d-channels x 32 states (its half).
__global__ __launch_bounds__(256) void final_kernel(
    const float* __restrict__ At, const float* __restrict__ Bt,
    const float* __restrict__ Ct, const float* __restrict__ xc,
    const float* __restrict__ Hst, const float* __restrict__ D_skip,
    float* __restrict__ out) {
  __shared__ __align__(16) float Al[16][kS];
  __shared__ __align__(16) float Bl[16][kS];
  __shared__ __align__(16) float Cl[16][kS];
  __shared__ __align__(16) float xcl[16][512];

  const int tid = threadIdx.x;
  const int bc = blockIdx.x >> 1;     // b*kTC + c
  const int half = blockIdx.x & 1;    // which 512-d half
  const int b = bc / kTC, c = bc % kTC;
  const int w = tid >> 6;             // wave 0..3
  const int lane = tid & 63;
  const int dl = lane & 31;
  const int sh = lane >> 5;           // s-half 0/1
  const int dbase = half * 512;
  const int d0 = dbase + w * 128;     // wave d-base
  const int t0 = c * kQ;
  const int clen = min(kQ, kLc - t0);

  float h[4][32];
  {
    size_t hb = (size_t)bc * kS * kD;
#pragma unroll
    for (int j = 0; j < 32; ++j) {
      int s = sh * 32 + j;
#pragma unroll
      for (int v = 0; v < 4; ++v)
        h[v][j] = Hst[hb + (size_t)s * kD + d0 + v * 32 + dl];
    }
  }
  float dskip[4];
#pragma unroll
  for (int v = 0; v < 4; ++v) dskip[v] = D_skip[d0 + v * 32 + dl];

  const size_t baseS = ((size_t)b * kLc + t0) * kS;
  const size_t baseD = ((size_t)b * kLc + t0) * kD;

  for (int tile = 0; tile < clen; tile += 16) {
    int sl = min(16, clen - tile);
    __syncthreads();
    // stage A/B/C [16][64]: 256 threads = 16 tt x 16 s-quads (unguarded:
    // tail-chunk overreads land in adjacent ws buffers, values unused)
    {
      int tt = tid >> 4, sq = tid & 15;
      size_t g = baseS + (size_t)(tile + tt) * kS + sq * 4;
      *(float4*)&Al[tt][sq * 4] = *(const float4*)(At + g);
      *(float4*)&Bl[tt][sq * 4] = *(const float4*)(Bt + g);
      *(float4*)&Cl[tt][sq * 4] = *(const float4*)(Ct + g);
    }
    // stage xc [16][512]
#pragma unroll
    for (int p = 0; p < 8; ++p) {
      int i = p * 256 + tid;
      int tt = i >> 7, dq = i & 127;
      *(float4*)&xcl[tt][dq * 4] =
          *(const float4*)(xc + baseD + (size_t)(tile + tt) * kD + dbase + dq * 4);
    }
    __syncthreads();

    for (int tt = 0; tt < sl; ++tt) {
      float xcv[4], dot[4];
#pragma unroll
      for (int v = 0; v < 4; ++v) {
        xcv[v] = xcl[tt][w * 128 + v * 32 + dl];
        dot[v] = 0.f;
      }
#pragma unroll
      for (int q = 0; q < 8; ++q) {
        float4 a4 = *(const float4*)&Al[tt][sh * 32 + q * 4];
        float4 b4 = *(const float4*)&Bl[tt][sh * 32 + q * 4];
        float4 c4 = *(const float4*)&Cl[tt][sh * 32 + q * 4];
        const float* ap = (const float*)&a4;
        const float* bp = (const float*)&b4;
        const float* cp = (const float*)&c4;
#pragma unroll
        for (int j = 0; j < 4; ++j) {
          const int sidx = q * 4 + j;
#pragma unroll
          for (int v = 0; v < 4; ++v) {
            h[v][sidx] = fmaf(ap[j], h[v][sidx], bp[j] * xcv[v]);
            dot[v] = fmaf(cp[j], h[v][sidx], dot[v]);
          }
        }
      }
#pragma unroll
      for (int v = 0; v < 4; ++v)
        dot[v] += __shfl_xor(dot[v], 32, 64);  // combine the two s-halves
      // each half stores 2 of the 4 v-slots -> full 128-d coverage, coalesced
#pragma unroll
      for (int k = 0; k < 2; ++k) {
        int v = sh * 2 + k;
        out[baseD + (size_t)(tile + tt) * kD + d0 + v * 32 + dl] =
            fmaf(dskip[v], xcv[v], dot[v]);
      }
    }
  }
}

extern "C" void kernel_launch(void* const* d_in, const int* in_sizes, int n_in,
                              void* d_out, int out_size, void* d_ws, size_t ws_size,
                              hipStream_t stream) {
  const float* x      = (const float*)d_in[0];
  const float* a_hat  = (const float*)d_in[1];
  const float* W_U    = (const float*)d_in[2];
  const float* W_B    = (const float*)d_in[3];
  const float* b_B    = (const float*)d_in[4];
  const float* W_C    = (const float*)d_in[5];
  const float* b_C    = (const float*)d_in[6];
  const float* W_d1   = (const float*)d_in[7];
  const float* b_d1   = (const float*)d_in[8];
  const float* W_d2   = (const float*)d_in[9];
  const float* b_d2   = (const float*)d_in[10];
  const float* D_skip = (const float*)d_in[11];
  const float* conv_w = (const float*)d_in[12];
  const float* conv_b = (const float*)d_in[13];
  float* out = (float*)d_out;

  float* xc   = (float*)d_ws;                        // kM*kD
  float* raw  = xc + (size_t)kM * kD;                // kM*kNR
  float* At   = raw + (size_t)kM * kNR;              // kM*kS
  float* Bt   = At + (size_t)kM * kS;
  float* Ct   = Bt + (size_t)kM * kS;
  float* Bpre = Ct + (size_t)kM * kS;                // B*TC*Q*S
  float* dec  = Bpre + (size_t)kB * kTC * kQ * kS;   // B*TC*S
  float* Sc   = dec + (size_t)kB * kTC * kS;         // B*TC*S*D (becomes H)

  int convThreads = kB * kLc * (kD / 4);
  conv_kernel<<<(convThreads + 255) / 256, 256, 0, stream>>>(x, conv_w, conv_b, xc);

  dim3 ggrid((kM + 63) / 64, 4);
  gemm_kernel<<<ggrid, 256, 0, stream>>>(xc, W_U, W_B, W_C, W_d1, raw);

  epi_kernel<<<(kM * kS + 255) / 256, 256, 0, stream>>>(
      raw, b_B, b_C, b_d1, W_d2, b_d2, a_hat, At, Bt, Ct);

  prep_kernel<<<kB * kTC, 64, 0, stream>>>(At, Bt, Bpre, dec);

  dim3 pgrid(kD / 64, kB * kTC);
  pstate_kernel<<<pgrid, 256, 0, stream>>>(Bpre, xc, Sc);

  chscan_kernel<<<kB * kS, kD / 4, 0, stream>>>(dec, Sc);

  final_kernel<<<kB * kTC * 2, 256, 0, stream>>>(
      At, Bt, Ct, xc, Sc, D_skip, out);
}

// Round 6
// 213.718 us; speedup vs baseline: 1.2958x; 1.2873x over previous
//
#include <hip/hip_runtime.h>
#include <hip/hip_bf16.h>

namespace {
constexpr int kB   = 4;
constexpr int kL   = 2048;
constexpr int kLc  = 2051;   // L + 3
constexpr int kD   = 1024;
constexpr int kS   = 64;
constexpr int kM   = kB * kLc;  // 8204 flattened (b,t) rows
constexpr int kNR  = 256;       // raw row stride (196 real cols, padded)
constexpr int kQ   = 32;        // scan time-chunk length
constexpr int kTC  = (kLc + kQ - 1) / kQ;  // 65 chunks per batch
}

typedef __attribute__((ext_vector_type(8))) short bf16x8;
typedef __attribute__((ext_vector_type(4))) float f32x4;

__device__ __forceinline__ float siluf_(float v) {
  return v / (1.f + expf(-v));
}
__device__ __forceinline__ float softplusf_(float v) {
  return (v > 20.f) ? v : log1pf(expf(v));
}
__device__ __forceinline__ unsigned short f2bf_(float f) {
  unsigned u = __float_as_uint(f);
  unsigned r = u + 0x7FFF + ((u >> 16) & 1);
  return (unsigned short)(r >> 16);
}
__device__ __forceinline__ float bf2f_(unsigned short u) {
  return __uint_as_float(((unsigned)u) << 16);
}

// ---------------- K1: depthwise conv1d -> xc fp32 + xcb bf16 --------------
__global__ __launch_bounds__(256) void conv_kernel(
    const float* __restrict__ x, const float* __restrict__ cw,
    const float* __restrict__ cb, float* __restrict__ xc,
    unsigned short* __restrict__ xcb) {
  int idx = blockIdx.x * blockDim.x + threadIdx.x;
  const int D4 = kD / 4;
  if (idx >= kB * kLc * D4) return;
  int d4 = idx % D4;
  int bt = idx / D4;
  int t = bt % kLc;
  int b = bt / kLc;
  int d = d4 * 4;

  float4 w0 = *(const float4*)(cw + (size_t)(d + 0) * 4);
  float4 w1 = *(const float4*)(cw + (size_t)(d + 1) * 4);
  float4 w2 = *(const float4*)(cw + (size_t)(d + 2) * 4);
  float4 w3 = *(const float4*)(cw + (size_t)(d + 3) * 4);
  float4 acc = *(const float4*)(cb + d);

#pragma unroll
  for (int k = 0; k < 4; ++k) {
    int ti = t + k - 3;
    if (ti >= 0 && ti < kL) {
      float4 xv = *(const float4*)(x + ((size_t)b * kL + ti) * kD + d);
      acc.x = fmaf(((const float*)&w0)[k], xv.x, acc.x);
      acc.y = fmaf(((const float*)&w1)[k], xv.y, acc.y);
      acc.z = fmaf(((const float*)&w2)[k], xv.z, acc.z);
      acc.w = fmaf(((const float*)&w3)[k], xv.w, acc.w);
    }
  }
  *(float4*)(xc + (size_t)bt * kD + d) = acc;
  ushort4 bv;
  bv.x = f2bf_(acc.x);
  bv.y = f2bf_(acc.y);
  bv.z = f2bf_(acc.z);
  bv.w = f2bf_(acc.w);
  *(ushort4*)(xcb + (size_t)bt * kD + d) = bv;
}

// ---------------- K1b: pack Wcat [256 x 1024] bf16 ------------------------
__global__ __launch_bounds__(256) void wcat_kernel(
    const float* __restrict__ W_U, const float* __restrict__ W_B,
    const float* __restrict__ W_C, const float* __restrict__ W_d1,
    unsigned short* __restrict__ wcat) {
  int n = blockIdx.x;  // 0..255
  const float* src = nullptr;
  if (n < 64)        src = W_U + (size_t)n * kD;
  else if (n < 128)  src = W_B + (size_t)(n - 64) * kD;
  else if (n < 192)  src = W_C + (size_t)(n - 128) * kD;
  else if (n < 196)  src = W_d1 + (size_t)(n - 192) * kD;
  for (int k = threadIdx.x; k < kD; k += 256) {
    float v = src ? src[k] : 0.f;
    wcat[(size_t)n * kD + k] = f2bf_(v);
  }
}

// ---------------- K2a: raw = xcb @ Wcat^T via MFMA bf16 -------------------
// block = 32 M-rows; 4 waves: wave = (M-half 16 rows) x (N-half 128 cols).
__global__ __launch_bounds__(256) void gemm_mfma_kernel(
    const unsigned short* __restrict__ xcb,
    const unsigned short* __restrict__ wcat, float* __restrict__ raw) {
  int tid = threadIdx.x;
  int w = tid >> 6, lane = tid & 63;
  int m0 = blockIdx.x * 32 + (w >> 1) * 16;
  int n0 = (w & 1) * 128;
  int l15 = lane & 15, lk = lane >> 4;

  int arow = m0 + l15;
  if (arow > kM - 1) arow = kM - 1;  // clamp; OOB rows masked at store
  const unsigned short* ap = xcb + (size_t)arow * kD + lk * 8;
  const unsigned short* bp = wcat + (size_t)(n0 + l15) * kD + lk * 8;

  f32x4 acc0 = {0.f, 0.f, 0.f, 0.f}, acc1 = acc0, acc2 = acc0, acc3 = acc0;
  f32x4 acc4 = acc0, acc5 = acc0, acc6 = acc0, acc7 = acc0;

  for (int kb = 0; kb < kD; kb += 32) {
    bf16x8 a = *(const bf16x8*)(ap + kb);
    bf16x8 b0 = *(const bf16x8*)(bp + (size_t)0 * 16 * kD + kb);
    bf16x8 b1 = *(const bf16x8*)(bp + (size_t)1 * 16 * kD + kb);
    bf16x8 b2 = *(const bf16x8*)(bp + (size_t)2 * 16 * kD + kb);
    bf16x8 b3 = *(const bf16x8*)(bp + (size_t)3 * 16 * kD + kb);
    bf16x8 b4 = *(const bf16x8*)(bp + (size_t)4 * 16 * kD + kb);
    bf16x8 b5 = *(const bf16x8*)(bp + (size_t)5 * 16 * kD + kb);
    bf16x8 b6 = *(const bf16x8*)(bp + (size_t)6 * 16 * kD + kb);
    bf16x8 b7 = *(const bf16x8*)(bp + (size_t)7 * 16 * kD + kb);
    acc0 = __builtin_amdgcn_mfma_f32_16x16x32_bf16(a, b0, acc0, 0, 0, 0);
    acc1 = __builtin_amdgcn_mfma_f32_16x16x32_bf16(a, b1, acc1, 0, 0, 0);
    acc2 = __builtin_amdgcn_mfma_f32_16x16x32_bf16(a, b2, acc2, 0, 0, 0);
    acc3 = __builtin_amdgcn_mfma_f32_16x16x32_bf16(a, b3, acc3, 0, 0, 0);
    acc4 = __builtin_amdgcn_mfma_f32_16x16x32_bf16(a, b4, acc4, 0, 0, 0);
    acc5 = __builtin_amdgcn_mfma_f32_16x16x32_bf16(a, b5, acc5, 0, 0, 0);
    acc6 = __builtin_amdgcn_mfma_f32_16x16x32_bf16(a, b6, acc6, 0, 0, 0);
    acc7 = __builtin_amdgcn_mfma_f32_16x16x32_bf16(a, b7, acc7, 0, 0, 0);
  }

  // C/D layout (m89-verified): col = lane&15, row = (lane>>4)*4 + reg
  int crow0 = m0 + lk * 4;
  f32x4 accs[8] = {acc0, acc1, acc2, acc3, acc4, acc5, acc6, acc7};
#pragma unroll
  for (int nf = 0; nf < 8; ++nf) {
    int col = n0 + nf * 16 + l15;
#pragma unroll
    for (int r = 0; r < 4; ++r) {
      int row = crow0 + r;
      if (row < kM) raw[(size_t)row * kNR + col] = accs[nf][r];
    }
  }
}

// ---------------- K2b: epilogue -> At, Bt, Ct ----------------------------
__global__ __launch_bounds__(256) void epi_kernel(
    const float* __restrict__ raw,
    const float* __restrict__ b_B, const float* __restrict__ b_C,
    const float* __restrict__ b_d1, const float* __restrict__ W_d2,
    const float* __restrict__ b_d2, const float* __restrict__ a_hat,
    float* __restrict__ At, float* __restrict__ Bt, float* __restrict__ Ct) {
  int idx = blockIdx.x * blockDim.x + threadIdx.x;
  if (idx >= kM * kS) return;
  int s = idx & 63;
  int row = idx >> 6;
  const float* r = raw + (size_t)row * kNR;

  float u  = r[s];
  float rb = r[64 + s] + b_B[s];
  float rc = r[128 + s] + b_C[s];
  float f0 = siluf_(r[192] + b_d1[0]);
  float f1 = siluf_(r[193] + b_d1[1]);
  float f2 = siluf_(r[194] + b_d1[2]);
  float f3 = siluf_(r[195] + b_d1[3]);
  float z = fmaf(f0, W_d2[0], fmaf(f1, W_d2[1], fmaf(f2, W_d2[2], fmaf(f3, W_d2[3], b_d2[0]))));
  float delta = softplusf_(z);
  size_t o = (size_t)row * kS + s;
  At[o] = expf(delta * -expf(a_hat[s]));
  Bt[o] = rb * u;
  Ct[o] = rc;
}

// ---------------- K3a: per-chunk backward cumprod -------------------------
__global__ __launch_bounds__(64) void prep_kernel(
    const float* __restrict__ At, const float* __restrict__ Bt,
    float* __restrict__ Bpre, float* __restrict__ dec) {
  __shared__ __align__(16) float Aloc[kQ][kS];
  __shared__ __align__(16) float Bloc[kQ][kS];
  int tid = threadIdx.x;  // 64
  int bc = blockIdx.x;
  int b = bc / kTC, c = bc % kTC;
  int t0 = c * kQ;
  int clen = min(kQ, kLc - t0);
  size_t baseS = ((size_t)b * kLc + t0) * kS;

  for (int i = tid; i < kQ * (kS / 4); i += 64) {
    int tt = i >> 4;
    int sq = i & 15;
    float4 a = make_float4(1.f, 1.f, 1.f, 1.f);
    float4 bv = make_float4(0.f, 0.f, 0.f, 0.f);
    if (tt < clen) {
      a  = *(const float4*)(At + baseS + (size_t)tt * kS + sq * 4);
      bv = *(const float4*)(Bt + baseS + (size_t)tt * kS + sq * 4);
    }
    *(float4*)&Aloc[tt][sq * 4] = a;
    *(float4*)&Bloc[tt][sq * 4] = bv;
  }
  __syncthreads();
  int s = tid;
  float E = 1.f;
  for (int tt = kQ - 1; tt >= 0; --tt) {
    Bpre[((size_t)bc * kQ + tt) * kS + s] = E * Bloc[tt][s];
    E *= Aloc[tt][s];
  }
  dec[(size_t)bc * kS + s] = E;
}

// ---------------- K3b: partial end-state GEMM -> Sc (bf16) ----------------
__global__ __launch_bounds__(256) void pstate_kernel(
    const float* __restrict__ Bpre, const float* __restrict__ xc,
    unsigned short* __restrict__ Sc) {
  __shared__ __align__(16) float bpl[16][68];
  __shared__ __align__(16) float xl[16][68];
  int tid = threadIdx.x;
  int bc = blockIdx.y;
  int b = bc / kTC, c = bc % kTC;
  int d0 = blockIdx.x * 64;
  int tm = tid >> 4, tn = tid & 15;
  int srow = tid >> 4, scol = tid & 15;
  int t0 = c * kQ;

  float acc[4][4];
#pragma unroll
  for (int i = 0; i < 4; ++i)
#pragma unroll
    for (int j = 0; j < 4; ++j) acc[i][j] = 0.f;

  for (int kb = 0; kb < kQ; kb += 16) {
    __syncthreads();
    {
      float4 bv = *(const float4*)(Bpre + ((size_t)bc * kQ + kb + srow) * kS + scol * 4);
      int gt = t0 + kb + srow;
      if (gt > kLc - 1) gt = kLc - 1;  // clamp; Bpre is 0 there
      float4 xv = *(const float4*)(xc + ((size_t)b * kLc + gt) * kD + d0 + scol * 4);
      *(float4*)&bpl[srow][scol * 4] = bv;
      *(float4*)&xl[srow][scol * 4] = xv;
    }
    __syncthreads();
#pragma unroll
    for (int k = 0; k < 16; ++k) {
      float4 a = *(const float4*)&bpl[k][tm * 4];
      float4 w = *(const float4*)&xl[k][tn * 4];
      const float* ap = (const float*)&a;
      const float* wp = (const float*)&w;
#pragma unroll
      for (int i = 0; i < 4; ++i)
#pragma unroll
        for (int j = 0; j < 4; ++j) acc[i][j] = fmaf(ap[i], wp[j], acc[i][j]);
    }
  }
#pragma unroll
  for (int i = 0; i < 4; ++i) {
    ushort4 o;
    o.x = f2bf_(acc[i][0]);
    o.y = f2bf_(acc[i][1]);
    o.z = f2bf_(acc[i][2]);
    o.w = f2bf_(acc[i][3]);
    *(ushort4*)(Sc + ((size_t)bc * kS + tm * 4 + i) * kD + d0 + tn * 4) = o;
  }
}

// ---------------- K3c: cross-chunk state scan (in-place, fp32 regs) -------
__global__ __launch_bounds__(256) void chscan_kernel(
    const float* __restrict__ dec, unsigned short* __restrict__ Sc) {
  int bs = blockIdx.x;           // b*kS + s
  int dq = threadIdx.x;          // 0..255 -> d quad
  int b = bs >> 6, s = bs & 63;
  float rx = 0.f, ry = 0.f, rz = 0.f, rw = 0.f;
  for (int c = 0; c < kTC; ++c) {
    size_t off = ((size_t)(b * kTC + c) * kS + s) * kD + dq * 4;
    ushort4 t4 = *(const ushort4*)(Sc + off);
    ushort4 o;
    o.x = f2bf_(rx); o.y = f2bf_(ry); o.z = f2bf_(rz); o.w = f2bf_(rw);
    *(ushort4*)(Sc + off) = o;   // H_before[c]
    float dc = dec[(size_t)(b * kTC + c) * kS + s];
    rx = fmaf(dc, rx, bf2f_(t4.x));
    ry = fmaf(dc, ry, bf2f_(t4.y));
    rz = fmaf(dc, rz, bf2f_(t4.z));
    rw = fmaf(dc, rw, bf2f_(t4.w));
  }
}

// ---------------- K3d: final chunked scan (V=4 d/thread, s-split-2) -------
__global__ __launch_bounds__(256) void final_kernel(
    const float* __restrict__ At, const float* __restrict__ Bt,
    const float* __restrict__ Ct, const float* __restrict__ xc,
    const unsigned short* __restrict__ Hst, const float* __restrict__ D_skip,
    float* __restrict__ out) {
  __shared__ __align__(16) float Al[16][kS];
  __shared__ __align__(16) float Bl[16][kS];
  __shared__ __align__(16) float Cl[16][kS];
  __shared__ __align__(16) float xcl[16][512];

  const int tid = threadIdx.x;
  const int bc = blockIdx.x >> 1;     // b*kTC + c
  const int half = blockIdx.x & 1;    // which 512-d half
  const int b = bc / kTC, c = bc % kTC;
  const int w = tid >> 6;             // wave 0..3
  const int lane = tid & 63;
  const int dl = lane & 31;
  const int sh = lane >> 5;           // s-half 0/1
  const int dbase = half * 512;
  const int d0 = dbase + w * 128;     // wave d-base
  const int t0 = c * kQ;
  const int clen = min(kQ, kLc - t0);

  float h[4][32];
  {
    size_t hb = (size_t)bc * kS * kD;
#pragma unroll
    for (int j = 0; j < 32; ++j) {
      int s = sh * 32 + j;
#pragma unroll
      for (int v = 0; v < 4; ++v)
        h[v][j] = bf2f_(Hst[hb + (size_t)s * kD + d0 + v * 32 + dl]);
    }
  }
  float dskip[4];
#pragma unroll
  for (int v = 0; v < 4; ++v) dskip[v] = D_skip[d0 + v * 32 + dl];

  const size_t baseS = ((size_t)b * kLc + t0) * kS;
  const size_t baseD = ((size_t)b * kLc + t0) * kD;

  for (int tile = 0; tile < clen; tile += 16) {
    int sl = min(16, clen - tile);
    __syncthreads();
    // stage A/B/C [16][64]; tail overreads land in adjacent ws buffers
    {
      int tt = tid >> 4, sq = tid & 15;
      size_t g = baseS + (size_t)(tile + tt) * kS + sq * 4;
      *(float4*)&Al[tt][sq * 4] = *(const float4*)(At + g);
      *(float4*)&Bl[tt][sq * 4] = *(const float4*)(Bt + g);
      *(float4*)&Cl[tt][sq * 4] = *(const float4*)(Ct + g);
    }
    // stage xc [16][512]
#pragma unroll
    for (int p = 0; p < 8; ++p) {
      int i = p * 256 + tid;
      int tt = i >> 7, dq = i & 127;
      *(float4*)&xcl[tt][dq * 4] =
          *(const float4*)(xc + baseD + (size_t)(tile + tt) * kD + dbase + dq * 4);
    }
    __syncthreads();

    for (int tt = 0; tt < sl; ++tt) {
      float xcv[4], dot[4];
#pragma unroll
      for (int v = 0; v < 4; ++v) {
        xcv[v] = xcl[tt][w * 128 + v * 32 + dl];
        dot[v] = 0.f;
      }
#pragma unroll
      for (int q = 0; q < 8; ++q) {
        float4 a4 = *(const float4*)&Al[tt][sh * 32 + q * 4];
        float4 b4 = *(const float4*)&Bl[tt][sh * 32 + q * 4];
        float4 c4 = *(const float4*)&Cl[tt][sh * 32 + q * 4];
        const float* ap = (const float*)&a4;
        const float* bp = (const float*)&b4;
        const float* cp = (const float*)&c4;
#pragma unroll
        for (int j = 0; j < 4; ++j) {
          const int sidx = q * 4 + j;
#pragma unroll
          for (int v = 0; v < 4; ++v) {
            h[v][sidx] = fmaf(ap[j], h[v][sidx], bp[j] * xcv[v]);
            dot[v] = fmaf(cp[j], h[v][sidx], dot[v]);
          }
        }
      }
#pragma unroll
      for (int v = 0; v < 4; ++v)
        dot[v] += __shfl_xor(dot[v], 32, 64);  // combine the two s-halves
#pragma unroll
      for (int k = 0; k < 2; ++k) {
        int v = sh * 2 + k;
        out[baseD + (size_t)(tile + tt) * kD + d0 + v * 32 + dl] =
            fmaf(dskip[v], xcv[v], dot[v]);
      }
    }
  }
}

extern "C" void kernel_launch(void* const* d_in, const int* in_sizes, int n_in,
                              void* d_out, int out_size, void* d_ws, size_t ws_size,
                              hipStream_t stream) {
  const float* x      = (const float*)d_in[0];
  const float* a_hat  = (const float*)d_in[1];
  const float* W_U    = (const float*)d_in[2];
  const float* W_B    = (const float*)d_in[3];
  const float* b_B    = (const float*)d_in[4];
  const float* W_C    = (const float*)d_in[5];
  const float* b_C    = (const float*)d_in[6];
  const float* W_d1   = (const float*)d_in[7];
  const float* b_d1   = (const float*)d_in[8];
  const float* W_d2   = (const float*)d_in[9];
  const float* b_d2   = (const float*)d_in[10];
  const float* D_skip = (const float*)d_in[11];
  const float* conv_w = (const float*)d_in[12];
  const float* conv_b = (const float*)d_in[13];
  float* out = (float*)d_out;

  float* xc   = (float*)d_ws;                        // kM*kD
  float* raw  = xc + (size_t)kM * kD;                // kM*kNR
  float* At   = raw + (size_t)kM * kNR;              // kM*kS
  float* Bt   = At + (size_t)kM * kS;
  float* Ct   = Bt + (size_t)kM * kS;
  float* Bpre = Ct + (size_t)kM * kS;                // B*TC*Q*S
  float* dec  = Bpre + (size_t)kB * kTC * kQ * kS;   // B*TC*S
  unsigned short* xcb  = (unsigned short*)(dec + (size_t)kB * kTC * kS);  // kM*kD bf16
  unsigned short* wcat = xcb + (size_t)kM * kD;      // 256*1024 bf16
  unsigned short* Sc   = wcat + (size_t)256 * kD;    // B*TC*S*D bf16 (becomes H)

  int convThreads = kB * kLc * (kD / 4);
  conv_kernel<<<(convThreads + 255) / 256, 256, 0, stream>>>(x, conv_w, conv_b, xc, xcb);

  wcat_kernel<<<256, 256, 0, stream>>>(W_U, W_B, W_C, W_d1, wcat);

  gemm_mfma_kernel<<<(kM + 31) / 32, 256, 0, stream>>>(xcb, wcat, raw);

  epi_kernel<<<(kM * kS + 255) / 256, 256, 0, stream>>>(
      raw, b_B, b_C, b_d1, W_d2, b_d2, a_hat, At, Bt, Ct);

  prep_kernel<<<kB * kTC, 64, 0, stream>>>(At, Bt, Bpre, dec);

  dim3 pgrid(kD / 64, kB * kTC);
  pstate_kernel<<<pgrid, 256, 0, stream>>>(Bpre, xc, Sc);

  chscan_kernel<<<kB * kS, kD / 4, 0, stream>>>(dec, Sc);

  final_kernel<<<kB * kTC * 2, 256, 0, stream>>>(
      At, Bt, Ct, xc, Sc, D_skip, out);
}

// Round 7
// 197.454 us; speedup vs baseline: 1.4025x; 1.0824x over previous
//
#include <hip/hip_runtime.h>
#include <hip/hip_bf16.h>

namespace {
constexpr int kB   = 4;
constexpr int kL   = 2048;
constexpr int kLc  = 2051;   // L + 3
constexpr int kD   = 1024;
constexpr int kS   = 64;
constexpr int kM   = kB * kLc;  // 8204 flattened (b,t) rows
constexpr int kNR  = 256;       // raw row stride (196 real cols, padded)
constexpr int kQ   = 32;        // scan time-chunk length
constexpr int kTC  = (kLc + kQ - 1) / kQ;  // 65 chunks per batch
}

typedef __attribute__((ext_vector_type(8))) short bf16x8;
typedef __attribute__((ext_vector_type(4))) float f32x4;
typedef __attribute__((ext_vector_type(8))) unsigned short u16x8;

__device__ __forceinline__ float siluf_(float v) {
  return v / (1.f + expf(-v));
}
__device__ __forceinline__ float softplusf_(float v) {
  return (v > 20.f) ? v : log1pf(expf(v));
}
__device__ __forceinline__ unsigned short f2bf_(float f) {
  unsigned u = __float_as_uint(f);
  unsigned r = u + 0x7FFF + ((u >> 16) & 1);
  return (unsigned short)(r >> 16);
}
__device__ __forceinline__ float bf2f_(unsigned short u) {
  return __uint_as_float(((unsigned)u) << 16);
}

// ---------------- K1: depthwise conv1d -> xcb bf16 ------------------------
__global__ __launch_bounds__(256) void conv_kernel(
    const float* __restrict__ x, const float* __restrict__ cw,
    const float* __restrict__ cb, unsigned short* __restrict__ xcb) {
  int idx = blockIdx.x * blockDim.x + threadIdx.x;
  const int D4 = kD / 4;
  if (idx >= kB * kLc * D4) return;
  int d4 = idx % D4;
  int bt = idx / D4;
  int t = bt % kLc;
  int b = bt / kLc;
  int d = d4 * 4;

  float4 w0 = *(const float4*)(cw + (size_t)(d + 0) * 4);
  float4 w1 = *(const float4*)(cw + (size_t)(d + 1) * 4);
  float4 w2 = *(const float4*)(cw + (size_t)(d + 2) * 4);
  float4 w3 = *(const float4*)(cw + (size_t)(d + 3) * 4);
  float4 acc = *(const float4*)(cb + d);

#pragma unroll
  for (int k = 0; k < 4; ++k) {
    int ti = t + k - 3;
    if (ti >= 0 && ti < kL) {
      float4 xv = *(const float4*)(x + ((size_t)b * kL + ti) * kD + d);
      acc.x = fmaf(((const float*)&w0)[k], xv.x, acc.x);
      acc.y = fmaf(((const float*)&w1)[k], xv.y, acc.y);
      acc.z = fmaf(((const float*)&w2)[k], xv.z, acc.z);
      acc.w = fmaf(((const float*)&w3)[k], xv.w, acc.w);
    }
  }
  ushort4 bv;
  bv.x = f2bf_(acc.x);
  bv.y = f2bf_(acc.y);
  bv.z = f2bf_(acc.z);
  bv.w = f2bf_(acc.w);
  *(ushort4*)(xcb + (size_t)bt * kD + d) = bv;
}

// ---------------- K1b: pack Wcat [256 x 1024] bf16 ------------------------
__global__ __launch_bounds__(256) void wcat_kernel(
    const float* __restrict__ W_U, const float* __restrict__ W_B,
    const float* __restrict__ W_C, const float* __restrict__ W_d1,
    unsigned short* __restrict__ wcat) {
  int n = blockIdx.x;  // 0..255
  const float* src = nullptr;
  if (n < 64)        src = W_U + (size_t)n * kD;
  else if (n < 128)  src = W_B + (size_t)(n - 64) * kD;
  else if (n < 192)  src = W_C + (size_t)(n - 128) * kD;
  else if (n < 196)  src = W_d1 + (size_t)(n - 192) * kD;
  for (int k = threadIdx.x; k < kD; k += 256) {
    float v = src ? src[k] : 0.f;
    wcat[(size_t)n * kD + k] = f2bf_(v);
  }
}

// ---------------- K2a: raw = xcb @ Wcat^T via MFMA bf16 -------------------
// grid (ceil(kM/32), 2): block = 32M x 128N; wave = 16M x 64N (4 frags).
__global__ __launch_bounds__(256) void gemm_mfma_kernel(
    const unsigned short* __restrict__ xcb,
    const unsigned short* __restrict__ wcat, float* __restrict__ raw) {
  int tid = threadIdx.x;
  int w = tid >> 6, lane = tid & 63;
  int m0 = blockIdx.x * 32 + (w >> 1) * 16;
  int n0 = blockIdx.y * 128 + (w & 1) * 64;
  int l15 = lane & 15, lk = lane >> 4;

  int arow = m0 + l15;
  if (arow > kM - 1) arow = kM - 1;  // clamp; OOB rows masked at store
  const unsigned short* ap = xcb + (size_t)arow * kD + lk * 8;
  const unsigned short* bp = wcat + (size_t)(n0 + l15) * kD + lk * 8;

  f32x4 acc0 = {0.f, 0.f, 0.f, 0.f}, acc1 = acc0, acc2 = acc0, acc3 = acc0;

  for (int kb = 0; kb < kD; kb += 32) {
    bf16x8 a = *(const bf16x8*)(ap + kb);
    bf16x8 b0 = *(const bf16x8*)(bp + (size_t)0 * 16 * kD + kb);
    bf16x8 b1 = *(const bf16x8*)(bp + (size_t)1 * 16 * kD + kb);
    bf16x8 b2 = *(const bf16x8*)(bp + (size_t)2 * 16 * kD + kb);
    bf16x8 b3 = *(const bf16x8*)(bp + (size_t)3 * 16 * kD + kb);
    acc0 = __builtin_amdgcn_mfma_f32_16x16x32_bf16(a, b0, acc0, 0, 0, 0);
    acc1 = __builtin_amdgcn_mfma_f32_16x16x32_bf16(a, b1, acc1, 0, 0, 0);
    acc2 = __builtin_amdgcn_mfma_f32_16x16x32_bf16(a, b2, acc2, 0, 0, 0);
    acc3 = __builtin_amdgcn_mfma_f32_16x16x32_bf16(a, b3, acc3, 0, 0, 0);
  }

  // C/D layout (m89-verified): col = lane&15, row = (lane>>4)*4 + reg
  int crow0 = m0 + lk * 4;
  f32x4 accs[4] = {acc0, acc1, acc2, acc3};
#pragma unroll
  for (int nf = 0; nf < 4; ++nf) {
    int col = n0 + nf * 16 + l15;
#pragma unroll
    for (int r = 0; r < 4; ++r) {
      int row = crow0 + r;
      if (row < kM) raw[(size_t)row * kNR + col] = accs[nf][r];
    }
  }
}

// ---------------- K2b: epilogue -> At, Bt, Ct ----------------------------
__global__ __launch_bounds__(256) void epi_kernel(
    const float* __restrict__ raw,
    const float* __restrict__ b_B, const float* __restrict__ b_C,
    const float* __restrict__ b_d1, const float* __restrict__ W_d2,
    const float* __restrict__ b_d2, const float* __restrict__ a_hat,
    float* __restrict__ At, float* __restrict__ Bt, float* __restrict__ Ct) {
  int idx = blockIdx.x * blockDim.x + threadIdx.x;
  if (idx >= kM * kS) return;
  int s = idx & 63;
  int row = idx >> 6;
  const float* r = raw + (size_t)row * kNR;

  float u  = r[s];
  float rb = r[64 + s] + b_B[s];
  float rc = r[128 + s] + b_C[s];
  float f0 = siluf_(r[192] + b_d1[0]);
  float f1 = siluf_(r[193] + b_d1[1]);
  float f2 = siluf_(r[194] + b_d1[2]);
  float f3 = siluf_(r[195] + b_d1[3]);
  float z = fmaf(f0, W_d2[0], fmaf(f1, W_d2[1], fmaf(f2, W_d2[2], fmaf(f3, W_d2[3], b_d2[0]))));
  float delta = softplusf_(z);
  size_t o = (size_t)row * kS + s;
  At[o] = expf(delta * -expf(a_hat[s]));
  Bt[o] = rb * u;
  Ct[o] = rc;
}

// ---------------- K3a: per-chunk backward cumprod (segmented) -------------
// 256 thr = s(64) x seg(4); serial 8 steps per thread + 3-mul suffix.
__global__ __launch_bounds__(256) void prep_kernel(
    const float* __restrict__ At, const float* __restrict__ Bt,
    float* __restrict__ Bpre, float* __restrict__ dec) {
  __shared__ __align__(16) float Aloc[kQ][kS];
  __shared__ __align__(16) float Bloc[kQ][kS];
  __shared__ float prodl[4][kS];
  int tid = threadIdx.x;
  int bc = blockIdx.x;
  int b = bc / kTC, c = bc % kTC;
  int t0 = c * kQ;
  int clen = min(kQ, kLc - t0);
  size_t baseS = ((size_t)b * kLc + t0) * kS;

  for (int i = tid; i < kQ * (kS / 4); i += 256) {
    int tt = i >> 4;
    int sq = i & 15;
    float4 a = make_float4(1.f, 1.f, 1.f, 1.f);
    float4 bv = make_float4(0.f, 0.f, 0.f, 0.f);
    if (tt < clen) {
      a  = *(const float4*)(At + baseS + (size_t)tt * kS + sq * 4);
      bv = *(const float4*)(Bt + baseS + (size_t)tt * kS + sq * 4);
    }
    *(float4*)&Aloc[tt][sq * 4] = a;
    *(float4*)&Bloc[tt][sq * 4] = bv;
  }
  __syncthreads();
  int s = tid & 63;
  int seg = tid >> 6;   // 0..3, 8 steps each
  float p = 1.f;
#pragma unroll
  for (int j = 0; j < 8; ++j) p *= Aloc[seg * 8 + j][s];
  prodl[seg][s] = p;
  __syncthreads();
  float E = 1.f;
#pragma unroll
  for (int g = 0; g < 4; ++g)
    if (g > seg) E *= prodl[g][s];
#pragma unroll
  for (int j = 7; j >= 0; --j) {
    int tt = seg * 8 + j;
    Bpre[((size_t)bc * kQ + tt) * kS + s] = E * Bloc[tt][s];
    E *= Aloc[tt][s];
  }
  if (seg == 0) dec[(size_t)bc * kS + s] = E;  // = prod of all 32
}

// ---------------- K3b: partial end-state GEMM -> Sc (bf16) ----------------
__global__ __launch_bounds__(256) void pstate_kernel(
    const float* __restrict__ Bpre, const unsigned short* __restrict__ xcb,
    unsigned short* __restrict__ Sc) {
  __shared__ __align__(16) float bpl[16][68];
  __shared__ __align__(16) float xl[16][68];
  int tid = threadIdx.x;
  int bc = blockIdx.y;
  int b = bc / kTC, c = bc % kTC;
  int d0 = blockIdx.x * 64;
  int tm = tid >> 4, tn = tid & 15;
  int srow = tid >> 4, scol = tid & 15;
  int t0 = c * kQ;

  float acc[4][4];
#pragma unroll
  for (int i = 0; i < 4; ++i)
#pragma unroll
    for (int j = 0; j < 4; ++j) acc[i][j] = 0.f;

  for (int kb = 0; kb < kQ; kb += 16) {
    __syncthreads();
    {
      float4 bv = *(const float4*)(Bpre + ((size_t)bc * kQ + kb + srow) * kS + scol * 4);
      int gt = t0 + kb + srow;
      if (gt > kLc - 1) gt = kLc - 1;  // clamp; Bpre is 0 there
      ushort4 xv = *(const ushort4*)(xcb + ((size_t)b * kLc + gt) * kD + d0 + scol * 4);
      *(float4*)&bpl[srow][scol * 4] = bv;
      xl[srow][scol * 4 + 0] = bf2f_(xv.x);
      xl[srow][scol * 4 + 1] = bf2f_(xv.y);
      xl[srow][scol * 4 + 2] = bf2f_(xv.z);
      xl[srow][scol * 4 + 3] = bf2f_(xv.w);
    }
    __syncthreads();
#pragma unroll
    for (int k = 0; k < 16; ++k) {
      float4 a = *(const float4*)&bpl[k][tm * 4];
      float4 w = *(const float4*)&xl[k][tn * 4];
      const float* ap = (const float*)&a;
      const float* wp = (const float*)&w;
#pragma unroll
      for (int i = 0; i < 4; ++i)
#pragma unroll
        for (int j = 0; j < 4; ++j) acc[i][j] = fmaf(ap[i], wp[j], acc[i][j]);
    }
  }
#pragma unroll
  for (int i = 0; i < 4; ++i) {
    ushort4 o;
    o.x = f2bf_(acc[i][0]);
    o.y = f2bf_(acc[i][1]);
    o.z = f2bf_(acc[i][2]);
    o.w = f2bf_(acc[i][3]);
    *(ushort4*)(Sc + ((size_t)bc * kS + tm * 4 + i) * kD + d0 + tn * 4) = o;
  }
}

// ---------------- K3c: cross-chunk state scan (prefetched) ----------------
__global__ __launch_bounds__(256) void chscan_kernel(
    const float* __restrict__ dec, unsigned short* __restrict__ Sc) {
  int bs = blockIdx.x;           // b*kS + s
  int dq = threadIdx.x;          // 0..255 -> d quad
  int b = bs >> 6, s = bs & 63;
  const size_t cstride = (size_t)kS * kD;
  size_t off = ((size_t)(b * kTC) * kS + s) * kD + dq * 4;
  float rx = 0.f, ry = 0.f, rz = 0.f, rw = 0.f;
  ushort4 cur = *(const ushort4*)(Sc + off);
  for (int c = 0; c < kTC; ++c) {
    ushort4 nxt = make_ushort4(0, 0, 0, 0);
    if (c + 1 < kTC) nxt = *(const ushort4*)(Sc + off + cstride);
    float dc = dec[(size_t)(b * kTC + c) * kS + s];
    ushort4 o;
    o.x = f2bf_(rx); o.y = f2bf_(ry); o.z = f2bf_(rz); o.w = f2bf_(rw);
    *(ushort4*)(Sc + off) = o;   // H_before[c]
    rx = fmaf(dc, rx, bf2f_(cur.x));
    ry = fmaf(dc, ry, bf2f_(cur.y));
    rz = fmaf(dc, rz, bf2f_(cur.z));
    rw = fmaf(dc, rw, bf2f_(cur.w));
    cur = nxt;
    off += cstride;
  }
}

// ---------------- K3d: final chunked scan (Sg=4, V=8) ---------------------
// block = (bc, 512-d half); 4 waves; lane = (dl 0..15, sg = s-quarter 0..3).
// thread: h[8][16] = 8 d-channels x 16 states.
__global__ __launch_bounds__(256) void final_kernel(
    const float* __restrict__ At, const float* __restrict__ Bt,
    const float* __restrict__ Ct, const unsigned short* __restrict__ xcb,
    const unsigned short* __restrict__ Hst, const float* __restrict__ D_skip,
    float* __restrict__ out) {
  __shared__ __align__(16) float Al[16][kS];
  __shared__ __align__(16) float Bl[16][kS];
  __shared__ __align__(16) float Cl[16][kS];
  __shared__ __align__(16) unsigned short xclb[16][512];

  const int tid = threadIdx.x;
  const int bc = blockIdx.x >> 1;     // b*kTC + c
  const int half = blockIdx.x & 1;    // which 512-d half
  const int b = bc / kTC, c = bc % kTC;
  const int w = tid >> 6;             // wave 0..3
  const int lane = tid & 63;
  const int dl = lane & 15;
  const int sg = lane >> 4;           // s-quarter 0..3
  const int dbase = half * 512;
  const int d0 = dbase + w * 128;     // wave d-base
  const int t0 = c * kQ;
  const int clen = min(kQ, kLc - t0);

  float h[8][16];
  {
    size_t hb = (size_t)bc * kS * kD;
#pragma unroll
    for (int j = 0; j < 16; ++j) {
      int s = sg * 16 + j;
#pragma unroll
      for (int v = 0; v < 8; ++v)
        h[v][j] = bf2f_(Hst[hb + (size_t)s * kD + d0 + v * 16 + dl]);
    }
  }
  float dskip0 = D_skip[d0 + (sg * 2 + 0) * 16 + dl];
  float dskip1 = D_skip[d0 + (sg * 2 + 1) * 16 + dl];

  const size_t baseS = ((size_t)b * kLc + t0) * kS;
  const size_t baseD = ((size_t)b * kLc + t0) * kD;

  for (int tile = 0; tile < clen; tile += 16) {
    int sl = min(16, clen - tile);
    __syncthreads();
    // stage A/B/C [16][64] fp32; tail overreads land in adjacent ws buffers
    {
      int tt = tid >> 4, sq = tid & 15;
      size_t g = baseS + (size_t)(tile + tt) * kS + sq * 4;
      *(float4*)&Al[tt][sq * 4] = *(const float4*)(At + g);
      *(float4*)&Bl[tt][sq * 4] = *(const float4*)(Bt + g);
      *(float4*)&Cl[tt][sq * 4] = *(const float4*)(Ct + g);
    }
    // stage xcb [16][512] bf16
#pragma unroll
    for (int p = 0; p < 4; ++p) {
      int i = p * 256 + tid;
      int tt = i >> 6, dq = i & 63;
      *(u16x8*)&xclb[tt][dq * 8] =
          *(const u16x8*)(xcb + baseD + (size_t)(tile + tt) * kD + dbase + dq * 8);
    }
    __syncthreads();

    for (int tt = 0; tt < sl; ++tt) {
      float xcv[8], dot[8];
#pragma unroll
      for (int v = 0; v < 8; ++v) {
        xcv[v] = bf2f_(xclb[tt][w * 128 + v * 16 + dl]);
        dot[v] = 0.f;
      }
#pragma unroll
      for (int q = 0; q < 4; ++q) {
        float4 a4 = *(const float4*)&Al[tt][sg * 16 + q * 4];
        float4 b4 = *(const float4*)&Bl[tt][sg * 16 + q * 4];
        float4 c4 = *(const float4*)&Cl[tt][sg * 16 + q * 4];
        const float* ap = (const float*)&a4;
        const float* bp = (const float*)&b4;
        const float* cp = (const float*)&c4;
#pragma unroll
        for (int j = 0; j < 4; ++j) {
          const int sidx = q * 4 + j;
#pragma unroll
          for (int v = 0; v < 8; ++v) {
            h[v][sidx] = fmaf(ap[j], h[v][sidx], bp[j] * xcv[v]);
            dot[v] = fmaf(cp[j], h[v][sidx], dot[v]);
          }
        }
      }
      // reduce over the 4 s-quarters (lanes dl, dl^16, dl^32, dl^48)
#pragma unroll
      for (int v = 0; v < 8; ++v) {
        dot[v] += __shfl_xor(dot[v], 16);
        dot[v] += __shfl_xor(dot[v], 32);
      }
      // each sg stores v = sg*2, sg*2+1 -> full 128-d wave coverage
      int v0 = sg * 2;
      out[baseD + (size_t)(tile + tt) * kD + d0 + v0 * 16 + dl] =
          fmaf(dskip0, xcv[v0], dot[v0]);
      out[baseD + (size_t)(tile + tt) * kD + d0 + (v0 + 1) * 16 + dl] =
          fmaf(dskip1, xcv[v0 + 1], dot[v0 + 1]);
    }
  }
}

extern "C" void kernel_launch(void* const* d_in, const int* in_sizes, int n_in,
                              void* d_out, int out_size, void* d_ws, size_t ws_size,
                              hipStream_t stream) {
  const float* x      = (const float*)d_in[0];
  const float* a_hat  = (const float*)d_in[1];
  const float* W_U    = (const float*)d_in[2];
  const float* W_B    = (const float*)d_in[3];
  const float* b_B    = (const float*)d_in[4];
  const float* W_C    = (const float*)d_in[5];
  const float* b_C    = (const float*)d_in[6];
  const float* W_d1   = (const float*)d_in[7];
  const float* b_d1   = (const float*)d_in[8];
  const float* W_d2   = (const float*)d_in[9];
  const float* b_d2   = (const float*)d_in[10];
  const float* D_skip = (const float*)d_in[11];
  const float* conv_w = (const float*)d_in[12];
  const float* conv_b = (const float*)d_in[13];
  float* out = (float*)d_out;

  float* raw  = (float*)d_ws;                        // kM*kNR
  float* At   = raw + (size_t)kM * kNR;              // kM*kS
  float* Bt   = At + (size_t)kM * kS;
  float* Ct   = Bt + (size_t)kM * kS;
  float* Bpre = Ct + (size_t)kM * kS;                // B*TC*Q*S
  float* dec  = Bpre + (size_t)kB * kTC * kQ * kS;   // B*TC*S
  unsigned short* xcb  = (unsigned short*)(dec + (size_t)kB * kTC * kS);  // kM*kD bf16
  unsigned short* wcat = xcb + (size_t)kM * kD;      // 256*1024 bf16
  unsigned short* Sc   = wcat + (size_t)256 * kD;    // B*TC*S*D bf16 (becomes H)

  int convThreads = kB * kLc * (kD / 4);
  conv_kernel<<<(convThreads + 255) / 256, 256, 0, stream>>>(x, conv_w, conv_b, xcb);

  wcat_kernel<<<256, 256, 0, stream>>>(W_U, W_B, W_C, W_d1, wcat);

  dim3 ggrid((kM + 31) / 32, 2);
  gemm_mfma_kernel<<<ggrid, 256, 0, stream>>>(xcb, wcat, raw);

  epi_kernel<<<(kM * kS + 255) / 256, 256, 0, stream>>>(
      raw, b_B, b_C, b_d1, W_d2, b_d2, a_hat, At, Bt, Ct);

  prep_kernel<<<kB * kTC, 256, 0, stream>>>(At, Bt, Bpre, dec);

  dim3 pgrid(kD / 64, kB * kTC);
  pstate_kernel<<<pgrid, 256, 0, stream>>>(Bpre, xcb, Sc);

  chscan_kernel<<<kB * kS, kD / 4, 0, stream>>>(dec, Sc);

  final_kernel<<<kB * kTC * 2, 256, 0, stream>>>(
      At, Bt, Ct, xcb, Sc, D_skip, out);
}

// Round 8
// 190.313 us; speedup vs baseline: 1.4552x; 1.0375x over previous
//
#include <hip/hip_runtime.h>
#include <hip/hip_bf16.h>

namespace {
constexpr int kB   = 4;
constexpr int kL   = 2048;
constexpr int kLc  = 2051;   // L + 3
constexpr int kD   = 1024;
constexpr int kS   = 64;
constexpr int kM   = kB * kLc;  // 8204
constexpr int kNR  = 256;       // raw row stride (196 real cols)
constexpr int kQ   = 32;        // chunk length
constexpr int kTC  = (kLc + kQ - 1) / kQ;  // 65 chunks per batch
}

typedef __attribute__((ext_vector_type(8))) short bf16x8;
typedef __attribute__((ext_vector_type(4))) float f32x4;
typedef __attribute__((ext_vector_type(8))) unsigned short u16x8;

__device__ __forceinline__ float siluf_(float v) {
  return v / (1.f + expf(-v));
}
__device__ __forceinline__ float softplusf_(float v) {
  return (v > 20.f) ? v : log1pf(expf(v));
}
__device__ __forceinline__ unsigned short f2bf_(float f) {
  unsigned u = __float_as_uint(f);
  unsigned r = u + 0x7FFF + ((u >> 16) & 1);
  return (unsigned short)(r >> 16);
}
__device__ __forceinline__ float bf2f_(unsigned short u) {
  return __uint_as_float(((unsigned)u) << 16);
}

// ---------------- K1: depthwise conv1d -> xcb bf16 ------------------------
__global__ __launch_bounds__(256) void conv_kernel(
    const float* __restrict__ x, const float* __restrict__ cw,
    const float* __restrict__ cb, unsigned short* __restrict__ xcb) {
  int idx = blockIdx.x * blockDim.x + threadIdx.x;
  const int D4 = kD / 4;
  if (idx >= kB * kLc * D4) return;
  int d4 = idx % D4;
  int bt = idx / D4;
  int t = bt % kLc;
  int b = bt / kLc;
  int d = d4 * 4;

  float4 w0 = *(const float4*)(cw + (size_t)(d + 0) * 4);
  float4 w1 = *(const float4*)(cw + (size_t)(d + 1) * 4);
  float4 w2 = *(const float4*)(cw + (size_t)(d + 2) * 4);
  float4 w3 = *(const float4*)(cw + (size_t)(d + 3) * 4);
  float4 acc = *(const float4*)(cb + d);

#pragma unroll
  for (int k = 0; k < 4; ++k) {
    int ti = t + k - 3;
    if (ti >= 0 && ti < kL) {
      float4 xv = *(const float4*)(x + ((size_t)b * kL + ti) * kD + d);
      acc.x = fmaf(((const float*)&w0)[k], xv.x, acc.x);
      acc.y = fmaf(((const float*)&w1)[k], xv.y, acc.y);
      acc.z = fmaf(((const float*)&w2)[k], xv.z, acc.z);
      acc.w = fmaf(((const float*)&w3)[k], xv.w, acc.w);
    }
  }
  ushort4 bv;
  bv.x = f2bf_(acc.x);
  bv.y = f2bf_(acc.y);
  bv.z = f2bf_(acc.z);
  bv.w = f2bf_(acc.w);
  *(ushort4*)(xcb + (size_t)bt * kD + d) = bv;
}

// ---------------- K1b: pack Wcat [256 x 1024] bf16 ------------------------
__global__ __launch_bounds__(256) void wcat_kernel(
    const float* __restrict__ W_U, const float* __restrict__ W_B,
    const float* __restrict__ W_C, const float* __restrict__ W_d1,
    unsigned short* __restrict__ wcat) {
  int n = blockIdx.x;  // 0..255
  const float* src = nullptr;
  if (n < 64)        src = W_U + (size_t)n * kD;
  else if (n < 128)  src = W_B + (size_t)(n - 64) * kD;
  else if (n < 192)  src = W_C + (size_t)(n - 128) * kD;
  else if (n < 196)  src = W_d1 + (size_t)(n - 192) * kD;
  for (int k = threadIdx.x; k < kD; k += 256) {
    float v = src ? src[k] : 0.f;
    wcat[(size_t)n * kD + k] = f2bf_(v);
  }
}

// ---------------- K1c: transpose xcb -> xT [bc][d][tau] bf16 --------------
__global__ __launch_bounds__(256) void xpose_kernel(
    const unsigned short* __restrict__ xcb, unsigned short* __restrict__ xT) {
  int tid = threadIdx.x;
  int bc = blockIdx.x;
  int d0 = blockIdx.y * 128;
  int b = bc / kTC, c = bc % kTC;
  int t0 = c * kQ;
  int clen = min(kQ, kLc - t0);
  int dl = tid >> 1;
  int th = tid & 1;
  int d = d0 + dl;
  unsigned short v[16];
#pragma unroll
  for (int j = 0; j < 16; ++j) {
    int tau = th * 16 + j;
    v[j] = (tau < clen)
               ? xcb[((size_t)(b * kLc + t0 + tau)) * kD + d]
               : (unsigned short)0;
  }
  unsigned short* dst = xT + ((size_t)bc * kD + d) * kQ + th * 16;
  u16x8 o0, o1;
#pragma unroll
  for (int j = 0; j < 8; ++j) { o0[j] = v[j]; o1[j] = v[8 + j]; }
  *(u16x8*)dst = o0;
  *(u16x8*)(dst + 8) = o1;
}

// ---------------- K2: raw = xcb @ Wcat^T via MFMA bf16 --------------------
__global__ __launch_bounds__(256) void gemm_mfma_kernel(
    const unsigned short* __restrict__ xcb,
    const unsigned short* __restrict__ wcat, float* __restrict__ raw) {
  int tid = threadIdx.x;
  int w = tid >> 6, lane = tid & 63;
  int m0 = blockIdx.x * 32 + (w >> 1) * 16;
  int n0 = blockIdx.y * 128 + (w & 1) * 64;
  int l15 = lane & 15, lk = lane >> 4;

  int arow = m0 + l15;
  if (arow > kM - 1) arow = kM - 1;
  const unsigned short* ap = xcb + (size_t)arow * kD + lk * 8;
  const unsigned short* bp = wcat + (size_t)(n0 + l15) * kD + lk * 8;

  f32x4 acc0 = {0.f, 0.f, 0.f, 0.f}, acc1 = acc0, acc2 = acc0, acc3 = acc0;

  for (int kb = 0; kb < kD; kb += 32) {
    bf16x8 a = *(const bf16x8*)(ap + kb);
    bf16x8 b0 = *(const bf16x8*)(bp + (size_t)0 * 16 * kD + kb);
    bf16x8 b1 = *(const bf16x8*)(bp + (size_t)1 * 16 * kD + kb);
    bf16x8 b2 = *(const bf16x8*)(bp + (size_t)2 * 16 * kD + kb);
    bf16x8 b3 = *(const bf16x8*)(bp + (size_t)3 * 16 * kD + kb);
    acc0 = __builtin_amdgcn_mfma_f32_16x16x32_bf16(a, b0, acc0, 0, 0, 0);
    acc1 = __builtin_amdgcn_mfma_f32_16x16x32_bf16(a, b1, acc1, 0, 0, 0);
    acc2 = __builtin_amdgcn_mfma_f32_16x16x32_bf16(a, b2, acc2, 0, 0, 0);
    acc3 = __builtin_amdgcn_mfma_f32_16x16x32_bf16(a, b3, acc3, 0, 0, 0);
  }

  int crow0 = m0 + lk * 4;
  f32x4 accs[4] = {acc0, acc1, acc2, acc3};
#pragma unroll
  for (int nf = 0; nf < 4; ++nf) {
    int col = n0 + nf * 16 + l15;
#pragma unroll
    for (int r = 0; r < 4; ++r) {
      int row = crow0 + r;
      if (row < kM) raw[(size_t)row * kNR + col] = accs[nf][r];
    }
  }
}

// ---------------- K3: passA — selective params, G, C~, Bpre->Sc -----------
// block = one (b, chunk). Computes:
//   delta/Dloc (scalar cumsum), Bu/Cf, C~ (fp32), G (bf16), dec,
//   Sc[s][d] = sum_tau Bpre[s][tau]*x[tau][d] via MFMA.
__global__ __launch_bounds__(256) void passA_kernel(
    const float* __restrict__ raw, const unsigned short* __restrict__ xT,
    const float* __restrict__ b_B, const float* __restrict__ b_C,
    const float* __restrict__ b_d1, const float* __restrict__ W_d2,
    const float* __restrict__ b_d2, const float* __restrict__ a_hat,
    unsigned short* __restrict__ Gm, float* __restrict__ Ctf,
    unsigned short* __restrict__ Sc, float* __restrict__ dec) {
  __shared__ __align__(16) float Cfl[32][68];
  __shared__ __align__(16) float BulT[64][36];
  __shared__ __align__(16) unsigned short Bprel[64][40];
  __shared__ float deltal[32];
  __shared__ float Dloc[32];
  __shared__ float logAl[64];

  int tid = threadIdx.x;
  int bc = blockIdx.x;
  int b = bc / kTC, c = bc % kTC;
  int t0 = c * kQ;
  int clen = min(kQ, kLc - t0);

  if (tid < 64) logAl[tid] = -expf(a_hat[tid]);
  if (tid >= 64 && tid < 96) {
    int t = tid - 64;
    float r0 = 0.f, r1 = 0.f, r2 = 0.f, r3 = 0.f;
    if (t < clen) {
      const float* rp = raw + (size_t)(b * kLc + t0 + t) * kNR + 192;
      r0 = rp[0]; r1 = rp[1]; r2 = rp[2]; r3 = rp[3];
    }
    float f0 = siluf_(r0 + b_d1[0]);
    float f1 = siluf_(r1 + b_d1[1]);
    float f2 = siluf_(r2 + b_d1[2]);
    float f3 = siluf_(r3 + b_d1[3]);
    float z = fmaf(f0, W_d2[0],
              fmaf(f1, W_d2[1], fmaf(f2, W_d2[2], fmaf(f3, W_d2[3], b_d2[0]))));
    deltal[t] = softplusf_(z);
  }
  // Bu / Cf  (pad rows -> u=0 so Bu=0; Cf=b_C harmless, masked downstream)
  for (int p = 0; p < 8; ++p) {
    int idx = p * 256 + tid;
    int t = idx >> 6, s = idx & 63;
    float u = 0.f, rb = 0.f, rc = 0.f;
    if (t < clen) {
      const float* rp = raw + (size_t)(b * kLc + t0 + t) * kNR;
      u = rp[s]; rb = rp[64 + s]; rc = rp[128 + s];
    }
    BulT[s][t] = (rb + b_B[s]) * u;
    Cfl[t][s] = rc + b_C[s];
  }
  __syncthreads();
  if (tid < 32) {
    float sum = 0.f;
    for (int j = 0; j <= tid; ++j) sum += deltal[j];
    Dloc[tid] = sum;
  }
  __syncthreads();
  float Dend = Dloc[31];

  // C~ (fp32 for passB VALU)
  for (int p = 0; p < 8; ++p) {
    int idx = p * 256 + tid;
    int t = idx >> 6, s = idx & 63;
    Ctf[((size_t)bc * 32 + t) * kS + s] = Cfl[t][s] * __expf(Dloc[t] * logAl[s]);
  }
  // Bpre (bf16, LDS) — exponent (Dend - Dloc[tau])*logA <= 0, bounded
  for (int p = 0; p < 8; ++p) {
    int idx = p * 256 + tid;
    int s = idx >> 5, tau = idx & 31;
    Bprel[s][tau] = f2bf_(BulT[s][tau] * __expf((Dend - Dloc[tau]) * logAl[s]));
  }
  if (tid < 64) dec[(size_t)bc * kS + tid] = __expf(Dend * logAl[tid]);
  // G[t][tau] (masked lower-triangular), bf16
  for (int p = 0; p < 4; ++p) {
    int idx = p * 256 + tid;
    int t = idx >> 5, tau = idx & 31;
    float g = 0.f;
    if (tau <= t) {
      float dd = Dloc[t] - Dloc[tau];
      for (int s = 0; s < 64; ++s)
        g = fmaf(Cfl[t][s] * BulT[s][tau], __expf(dd * logAl[s]), g);
    }
    Gm[((size_t)bc * 32 + t) * kQ + tau] = f2bf_(g);
  }
  __syncthreads();

  // Sc = Bpre @ x^T via MFMA (A: Bprel[s][tau], B: xT[d][tau])
  int w = tid >> 6, lane = tid & 63;
  int l15 = lane & 15, lk = lane >> 4;
  int s0 = w * 16;
  bf16x8 afrag = *(const bf16x8*)&Bprel[s0 + l15][lk * 8];
  const unsigned short* xTb = xT + (size_t)bc * kD * kQ;
  unsigned short* ScB = Sc + (size_t)bc * kS * kD;
#pragma unroll 4
  for (int nt = 0; nt < 64; ++nt) {
    bf16x8 bfrag = *(const bf16x8*)(xTb + (size_t)(nt * 16 + l15) * kQ + lk * 8);
    f32x4 acc = {0.f, 0.f, 0.f, 0.f};
    acc = __builtin_amdgcn_mfma_f32_16x16x32_bf16(afrag, bfrag, acc, 0, 0, 0);
    int d = nt * 16 + l15;
#pragma unroll
    for (int r = 0; r < 4; ++r)
      ScB[(size_t)(s0 + lk * 4 + r) * kD + d] = f2bf_(acc[r]);
  }
}

// ---------------- K4: cross-chunk state scan (in-place Sc -> H_before) ----
__global__ __launch_bounds__(256) void chscan_kernel(
    const float* __restrict__ dec, unsigned short* __restrict__ Sc) {
  int bs = blockIdx.x;           // b*kS + s
  int dq = threadIdx.x;          // 0..255 -> d quad
  int b = bs >> 6, s = bs & 63;
  const size_t cstride = (size_t)kS * kD;
  size_t off = ((size_t)(b * kTC) * kS + s) * kD + dq * 4;
  float rx = 0.f, ry = 0.f, rz = 0.f, rw = 0.f;
  ushort4 cur = *(const ushort4*)(Sc + off);
  for (int c = 0; c < kTC; ++c) {
    ushort4 nxt = make_ushort4(0, 0, 0, 0);
    if (c + 1 < kTC) nxt = *(const ushort4*)(Sc + off + cstride);
    float dc = dec[(size_t)(b * kTC + c) * kS + s];
    ushort4 o;
    o.x = f2bf_(rx); o.y = f2bf_(ry); o.z = f2bf_(rz); o.w = f2bf_(rw);
    *(ushort4*)(Sc + off) = o;   // H_before[c]
    rx = fmaf(dc, rx, bf2f_(cur.x));
    ry = fmaf(dc, ry, bf2f_(cur.y));
    rz = fmaf(dc, rz, bf2f_(cur.z));
    rw = fmaf(dc, rw, bf2f_(cur.w));
    cur = nxt;
    off += cstride;
  }
}

// ---------------- K5: passB — y = G@x (MFMA) + C~@H0 (VALU) + ds*x --------
// grid (bc, quarter); wave covers 64 d, 4 n-tiles, M=32 (2 m-tiles).
__global__ __launch_bounds__(256) void passB_kernel(
    const unsigned short* __restrict__ Gm, const float* __restrict__ Ctf,
    const unsigned short* __restrict__ xT, const unsigned short* __restrict__ hSc,
    const unsigned short* __restrict__ xcb, const float* __restrict__ D_skip,
    float* __restrict__ out) {
  __shared__ __align__(16) float Ctl[32][68];
  __shared__ __align__(16) unsigned short Hl[64][264];

  int tid = threadIdx.x;
  int bc = blockIdx.x;
  int quarter = blockIdx.y;
  int b = bc / kTC, c = bc % kTC;
  int t0 = c * kQ;
  int clen = min(kQ, kLc - t0);
  int dq0 = quarter * 256;

  // stage C~ [32][64] f32 and H0 slab [64][256] bf16
  for (int p = 0; p < 8; ++p) {
    int idx = p * 256 + tid;
    int t = idx >> 6, s = idx & 63;
    Ctl[t][s] = Ctf[((size_t)bc * 32 + t) * kS + s];
  }
  const unsigned short* hb = hSc + (size_t)bc * kS * kD;
  for (int p = 0; p < 8; ++p) {
    int oct = p * 256 + tid;           // over 64*32 u16x8
    int s = oct >> 5, o = oct & 31;
    *(u16x8*)&Hl[s][o * 8] = *(const u16x8*)(hb + (size_t)s * kD + dq0 + o * 8);
  }
  __syncthreads();

  int w = tid >> 6, lane = tid & 63;
  int l15 = lane & 15, lk = lane >> 4;
  const unsigned short* Gb = Gm + (size_t)bc * 32 * kQ;
  bf16x8 a0 = *(const bf16x8*)(Gb + (size_t)(l15) * kQ + lk * 8);
  bf16x8 a1 = *(const bf16x8*)(Gb + (size_t)(16 + l15) * kQ + lk * 8);
  const unsigned short* xTb = xT + (size_t)bc * kD * kQ;
  size_t rowbase = (size_t)b * kLc + t0;
  int tb0 = lk * 4;

  f32x4 accA[4], accB[4];   // [nt] for m-tile 0 / 1
#pragma unroll
  for (int nt = 0; nt < 4; ++nt) {
    int d = dq0 + w * 64 + nt * 16 + l15;
    bf16x8 bfrag = *(const bf16x8*)(xTb + (size_t)d * kQ + lk * 8);
    f32x4 z = {0.f, 0.f, 0.f, 0.f};
    accA[nt] = __builtin_amdgcn_mfma_f32_16x16x32_bf16(a0, bfrag, z, 0, 0, 0);
    accB[nt] = __builtin_amdgcn_mfma_f32_16x16x32_bf16(a1, bfrag, z, 0, 0, 0);
  }
  // y_H0: acc += C~[t][s] * H0[s][d]
  for (int s = 0; s < 64; ++s) {
    float c0 = Ctl[tb0 + 0][s];
    float c1 = Ctl[tb0 + 1][s];
    float c2 = Ctl[tb0 + 2][s];
    float c3 = Ctl[tb0 + 3][s];
    float c4 = Ctl[16 + tb0 + 0][s];
    float c5 = Ctl[16 + tb0 + 1][s];
    float c6 = Ctl[16 + tb0 + 2][s];
    float c7 = Ctl[16 + tb0 + 3][s];
#pragma unroll
    for (int nt = 0; nt < 4; ++nt) {
      float hv = bf2f_(Hl[s][w * 64 + nt * 16 + l15]);
      accA[nt][0] = fmaf(c0, hv, accA[nt][0]);
      accA[nt][1] = fmaf(c1, hv, accA[nt][1]);
      accA[nt][2] = fmaf(c2, hv, accA[nt][2]);
      accA[nt][3] = fmaf(c3, hv, accA[nt][3]);
      accB[nt][0] = fmaf(c4, hv, accB[nt][0]);
      accB[nt][1] = fmaf(c5, hv, accB[nt][1]);
      accB[nt][2] = fmaf(c6, hv, accB[nt][2]);
      accB[nt][3] = fmaf(c7, hv, accB[nt][3]);
    }
  }
  // epilogue: + ds*x, store (guard t < clen)
#pragma unroll
  for (int nt = 0; nt < 4; ++nt) {
    int d = dq0 + w * 64 + nt * 16 + l15;
    float ds = D_skip[d];
#pragma unroll
    for (int r = 0; r < 4; ++r) {
      int t = tb0 + r;
      if (t < clen) {
        float xv = bf2f_(xcb[(rowbase + t) * kD + d]);
        out[(rowbase + t) * kD + d] = fmaf(ds, xv, accA[nt][r]);
      }
      int t2 = 16 + tb0 + r;
      if (t2 < clen) {
        float xv = bf2f_(xcb[(rowbase + t2) * kD + d]);
        out[(rowbase + t2) * kD + d] = fmaf(ds, xv, accB[nt][r]);
      }
    }
  }
}

extern "C" void kernel_launch(void* const* d_in, const int* in_sizes, int n_in,
                              void* d_out, int out_size, void* d_ws, size_t ws_size,
                              hipStream_t stream) {
  const float* x      = (const float*)d_in[0];
  const float* a_hat  = (const float*)d_in[1];
  const float* W_U    = (const float*)d_in[2];
  const float* W_B    = (const float*)d_in[3];
  const float* b_B    = (const float*)d_in[4];
  const float* W_C    = (const float*)d_in[5];
  const float* b_C    = (const float*)d_in[6];
  const float* W_d1   = (const float*)d_in[7];
  const float* b_d1   = (const float*)d_in[8];
  const float* W_d2   = (const float*)d_in[9];
  const float* b_d2   = (const float*)d_in[10];
  const float* D_skip = (const float*)d_in[11];
  const float* conv_w = (const float*)d_in[12];
  const float* conv_b = (const float*)d_in[13];
  float* out = (float*)d_out;

  char* w = (char*)d_ws;
  auto nextp = [&](size_t bytes) {
    char* p = w;
    w += (bytes + 255) & ~(size_t)255;
    return p;
  };
  unsigned short* xcb  = (unsigned short*)nextp((size_t)kM * kD * 2);
  unsigned short* wcat = (unsigned short*)nextp((size_t)256 * kD * 2);
  unsigned short* xT   = (unsigned short*)nextp((size_t)kB * kTC * kD * kQ * 2);
  float*          raw  = (float*)nextp((size_t)kM * kNR * 4);
  unsigned short* Gm   = (unsigned short*)nextp((size_t)kB * kTC * 32 * kQ * 2);
  float*          Ctf  = (float*)nextp((size_t)kB * kTC * 32 * kS * 4);
  float*          dec  = (float*)nextp((size_t)kB * kTC * kS * 4);
  unsigned short* Sc   = (unsigned short*)nextp((size_t)kB * kTC * kS * kD * 2);

  int convThreads = kB * kLc * (kD / 4);
  conv_kernel<<<(convThreads + 255) / 256, 256, 0, stream>>>(x, conv_w, conv_b, xcb);

  wcat_kernel<<<256, 256, 0, stream>>>(W_U, W_B, W_C, W_d1, wcat);

  dim3 xgrid(kB * kTC, kD / 128);
  xpose_kernel<<<xgrid, 256, 0, stream>>>(xcb, xT);

  dim3 ggrid((kM + 31) / 32, 2);
  gemm_mfma_kernel<<<ggrid, 256, 0, stream>>>(xcb, wcat, raw);

  passA_kernel<<<kB * kTC, 256, 0, stream>>>(
      raw, xT, b_B, b_C, b_d1, W_d2, b_d2, a_hat, Gm, Ctf, Sc, dec);

  chscan_kernel<<<kB * kS, kD / 4, 0, stream>>>(dec, Sc);

  dim3 bgrid(kB * kTC, 4);
  passB_kernel<<<bgrid, 256, 0, stream>>>(Gm, Ctf, xT, Sc, xcb, D_skip, out);
}

// Round 9
// 152.964 us; speedup vs baseline: 1.8105x; 1.2442x over previous
//
#include <hip/hip_runtime.h>
#include <hip/hip_bf16.h>

namespace {
constexpr int kB   = 4;
constexpr int kL   = 2048;
constexpr int kLc  = 2051;   // L + 3
constexpr int kD   = 1024;
constexpr int kS   = 64;
constexpr int kM   = kB * kLc;  // 8204
constexpr int kNR  = 256;       // raw row stride (196 real cols)
constexpr int kQ   = 32;        // chunk length
constexpr int kTC  = (kLc + kQ - 1) / kQ;  // 65 chunks per batch
}

typedef __attribute__((ext_vector_type(8))) short bf16x8;
typedef __attribute__((ext_vector_type(4))) float f32x4;
typedef __attribute__((ext_vector_type(8))) unsigned short u16x8;

__device__ __forceinline__ float siluf_(float v) {
  return v / (1.f + expf(-v));
}
__device__ __forceinline__ float softplusf_(float v) {
  return (v > 20.f) ? v : log1pf(expf(v));
}
__device__ __forceinline__ unsigned short f2bf_(float f) {
  unsigned u = __float_as_uint(f);
  unsigned r = u + 0x7FFF + ((u >> 16) & 1);
  return (unsigned short)(r >> 16);
}
__device__ __forceinline__ float bf2f_(unsigned short u) {
  return __uint_as_float(((unsigned)u) << 16);
}

// ---------------- K1: depthwise conv1d -> xcb bf16 ------------------------
__global__ __launch_bounds__(256) void conv_kernel(
    const float* __restrict__ x, const float* __restrict__ cw,
    const float* __restrict__ cb, unsigned short* __restrict__ xcb) {
  int idx = blockIdx.x * blockDim.x + threadIdx.x;
  const int D4 = kD / 4;
  if (idx >= kB * kLc * D4) return;
  int d4 = idx % D4;
  int bt = idx / D4;
  int t = bt % kLc;
  int b = bt / kLc;
  int d = d4 * 4;

  float4 w0 = *(const float4*)(cw + (size_t)(d + 0) * 4);
  float4 w1 = *(const float4*)(cw + (size_t)(d + 1) * 4);
  float4 w2 = *(const float4*)(cw + (size_t)(d + 2) * 4);
  float4 w3 = *(const float4*)(cw + (size_t)(d + 3) * 4);
  float4 acc = *(const float4*)(cb + d);

#pragma unroll
  for (int k = 0; k < 4; ++k) {
    int ti = t + k - 3;
    if (ti >= 0 && ti < kL) {
      float4 xv = *(const float4*)(x + ((size_t)b * kL + ti) * kD + d);
      acc.x = fmaf(((const float*)&w0)[k], xv.x, acc.x);
      acc.y = fmaf(((const float*)&w1)[k], xv.y, acc.y);
      acc.z = fmaf(((const float*)&w2)[k], xv.z, acc.z);
      acc.w = fmaf(((const float*)&w3)[k], xv.w, acc.w);
    }
  }
  ushort4 bv;
  bv.x = f2bf_(acc.x);
  bv.y = f2bf_(acc.y);
  bv.z = f2bf_(acc.z);
  bv.w = f2bf_(acc.w);
  *(ushort4*)(xcb + (size_t)bt * kD + d) = bv;
}

// ---------------- K1b: pack Wcat [256 x 1024] bf16 ------------------------
__global__ __launch_bounds__(256) void wcat_kernel(
    const float* __restrict__ W_U, const float* __restrict__ W_B,
    const float* __restrict__ W_C, const float* __restrict__ W_d1,
    unsigned short* __restrict__ wcat) {
  int n = blockIdx.x;  // 0..255
  const float* src = nullptr;
  if (n < 64)        src = W_U + (size_t)n * kD;
  else if (n < 128)  src = W_B + (size_t)(n - 64) * kD;
  else if (n < 192)  src = W_C + (size_t)(n - 128) * kD;
  else if (n < 196)  src = W_d1 + (size_t)(n - 192) * kD;
  for (int k = threadIdx.x; k < kD; k += 256) {
    float v = src ? src[k] : 0.f;
    wcat[(size_t)n * kD + k] = f2bf_(v);
  }
}

// ---------------- K1c: transpose xcb -> xT [bc][d][tau] bf16 --------------
__global__ __launch_bounds__(256) void xpose_kernel(
    const unsigned short* __restrict__ xcb, unsigned short* __restrict__ xT) {
  int tid = threadIdx.x;
  int bc = blockIdx.x;
  int d0 = blockIdx.y * 128;
  int b = bc / kTC, c = bc % kTC;
  int t0 = c * kQ;
  int clen = min(kQ, kLc - t0);
  int dl = tid >> 1;
  int th = tid & 1;
  int d = d0 + dl;
  unsigned short v[16];
#pragma unroll
  for (int j = 0; j < 16; ++j) {
    int tau = th * 16 + j;
    v[j] = (tau < clen)
               ? xcb[((size_t)(b * kLc + t0 + tau)) * kD + d]
               : (unsigned short)0;
  }
  unsigned short* dst = xT + ((size_t)bc * kD + d) * kQ + th * 16;
  u16x8 o0, o1;
#pragma unroll
  for (int j = 0; j < 8; ++j) { o0[j] = v[j]; o1[j] = v[8 + j]; }
  *(u16x8*)dst = o0;
  *(u16x8*)(dst + 8) = o1;
}

// ---------------- K2: raw = xcb @ Wcat^T via MFMA (reg-prefetched) --------
__global__ __launch_bounds__(256) void gemm_mfma_kernel(
    const unsigned short* __restrict__ xcb,
    const unsigned short* __restrict__ wcat, float* __restrict__ raw) {
  int tid = threadIdx.x;
  int w = tid >> 6, lane = tid & 63;
  int m0 = blockIdx.x * 32 + (w >> 1) * 16;
  int n0 = blockIdx.y * 128 + (w & 1) * 64;
  int l15 = lane & 15, lk = lane >> 4;

  int arow = m0 + l15;
  if (arow > kM - 1) arow = kM - 1;
  const unsigned short* ap = xcb + (size_t)arow * kD + lk * 8;
  const unsigned short* bp = wcat + (size_t)(n0 + l15) * kD + lk * 8;

  f32x4 acc0 = {0.f, 0.f, 0.f, 0.f}, acc1 = acc0, acc2 = acc0, acc3 = acc0;

  bf16x8 a  = *(const bf16x8*)(ap);
  bf16x8 b0 = *(const bf16x8*)(bp + (size_t)0 * 16 * kD);
  bf16x8 b1 = *(const bf16x8*)(bp + (size_t)1 * 16 * kD);
  bf16x8 b2 = *(const bf16x8*)(bp + (size_t)2 * 16 * kD);
  bf16x8 b3 = *(const bf16x8*)(bp + (size_t)3 * 16 * kD);

#pragma unroll 2
  for (int kb = 32; kb < kD; kb += 32) {
    bf16x8 an  = *(const bf16x8*)(ap + kb);
    bf16x8 b0n = *(const bf16x8*)(bp + (size_t)0 * 16 * kD + kb);
    bf16x8 b1n = *(const bf16x8*)(bp + (size_t)1 * 16 * kD + kb);
    bf16x8 b2n = *(const bf16x8*)(bp + (size_t)2 * 16 * kD + kb);
    bf16x8 b3n = *(const bf16x8*)(bp + (size_t)3 * 16 * kD + kb);
    acc0 = __builtin_amdgcn_mfma_f32_16x16x32_bf16(a, b0, acc0, 0, 0, 0);
    acc1 = __builtin_amdgcn_mfma_f32_16x16x32_bf16(a, b1, acc1, 0, 0, 0);
    acc2 = __builtin_amdgcn_mfma_f32_16x16x32_bf16(a, b2, acc2, 0, 0, 0);
    acc3 = __builtin_amdgcn_mfma_f32_16x16x32_bf16(a, b3, acc3, 0, 0, 0);
    a = an; b0 = b0n; b1 = b1n; b2 = b2n; b3 = b3n;
  }
  acc0 = __builtin_amdgcn_mfma_f32_16x16x32_bf16(a, b0, acc0, 0, 0, 0);
  acc1 = __builtin_amdgcn_mfma_f32_16x16x32_bf16(a, b1, acc1, 0, 0, 0);
  acc2 = __builtin_amdgcn_mfma_f32_16x16x32_bf16(a, b2, acc2, 0, 0, 0);
  acc3 = __builtin_amdgcn_mfma_f32_16x16x32_bf16(a, b3, acc3, 0, 0, 0);

  int crow0 = m0 + lk * 4;
  f32x4 accs[4] = {acc0, acc1, acc2, acc3};
#pragma unroll
  for (int nf = 0; nf < 4; ++nf) {
    int col = n0 + nf * 16 + l15;
#pragma unroll
    for (int r = 0; r < 4; ++r) {
      int row = crow0 + r;
      if (row < kM) raw[(size_t)row * kNR + col] = accs[nf][r];
    }
  }
}

// ---------------- K3: passA — delta/D, G, C~ (bf16), Bpre (bf16), dec -----
__global__ __launch_bounds__(256) void passA_kernel(
    const float* __restrict__ raw,
    const float* __restrict__ b_B, const float* __restrict__ b_C,
    const float* __restrict__ b_d1, const float* __restrict__ W_d2,
    const float* __restrict__ b_d2, const float* __restrict__ a_hat,
    unsigned short* __restrict__ Gm, unsigned short* __restrict__ Ctb,
    unsigned short* __restrict__ Bpre, float* __restrict__ dec) {
  __shared__ __align__(16) float Cfl[32][68];
  __shared__ __align__(16) float BulT[64][36];
  __shared__ float deltal[32];
  __shared__ float Dloc[32];
  __shared__ float logAl[64];

  int tid = threadIdx.x;
  int bc = blockIdx.x;
  int b = bc / kTC, c = bc % kTC;
  int t0 = c * kQ;
  int clen = min(kQ, kLc - t0);

  if (tid < 64) logAl[tid] = -expf(a_hat[tid]);
  if (tid >= 64 && tid < 96) {
    int t = tid - 64;
    float r0 = 0.f, r1 = 0.f, r2 = 0.f, r3 = 0.f;
    if (t < clen) {
      const float* rp = raw + (size_t)(b * kLc + t0 + t) * kNR + 192;
      r0 = rp[0]; r1 = rp[1]; r2 = rp[2]; r3 = rp[3];
    }
    float f0 = siluf_(r0 + b_d1[0]);
    float f1 = siluf_(r1 + b_d1[1]);
    float f2 = siluf_(r2 + b_d1[2]);
    float f3 = siluf_(r3 + b_d1[3]);
    float z = fmaf(f0, W_d2[0],
              fmaf(f1, W_d2[1], fmaf(f2, W_d2[2], fmaf(f3, W_d2[3], b_d2[0]))));
    deltal[t] = softplusf_(z);
  }
  // Bu / Cf  (pad rows -> u=0 so Bu=0)
  for (int p = 0; p < 8; ++p) {
    int idx = p * 256 + tid;
    int t = idx >> 6, s = idx & 63;
    float u = 0.f, rb = 0.f, rc = 0.f;
    if (t < clen) {
      const float* rp = raw + (size_t)(b * kLc + t0 + t) * kNR;
      u = rp[s]; rb = rp[64 + s]; rc = rp[128 + s];
    }
    BulT[s][t] = (rb + b_B[s]) * u;
    Cfl[t][s] = rc + b_C[s];
  }
  __syncthreads();
  if (tid < 32) {
    float sum = 0.f;
    for (int j = 0; j <= tid; ++j) sum += deltal[j];
    Dloc[tid] = sum;
  }
  __syncthreads();
  float Dend = Dloc[31];

  // C~ bf16 [t][s]
  for (int p = 0; p < 8; ++p) {
    int idx = p * 256 + tid;
    int t = idx >> 6, s = idx & 63;
    Ctb[(size_t)bc * 2048 + t * kS + s] =
        f2bf_(Cfl[t][s] * __expf(Dloc[t] * logAl[s]));
  }
  // Bpre bf16 [s][tau]
  for (int p = 0; p < 8; ++p) {
    int idx = p * 256 + tid;
    int s = idx >> 5, tau = idx & 31;
    Bpre[(size_t)bc * 2048 + s * kQ + tau] =
        f2bf_(BulT[s][tau] * __expf((Dend - Dloc[tau]) * logAl[s]));
  }
  if (tid < 64) dec[(size_t)bc * kS + tid] = __expf(Dend * logAl[tid]);
  // G[t][tau] lower-triangular, bf16
  for (int p = 0; p < 4; ++p) {
    int idx = p * 256 + tid;
    int t = idx >> 5, tau = idx & 31;
    float g = 0.f;
    if (tau <= t) {
      float dd = Dloc[t] - Dloc[tau];
      for (int s = 0; s < 64; ++s)
        g = fmaf(Cfl[t][s] * BulT[s][tau], __expf(dd * logAl[s]), g);
    }
    Gm[((size_t)bc * 32 + t) * kQ + tau] = f2bf_(g);
  }
}

// ---------------- K3b: ScT[d][s] = x @ Bpre^T via MFMA --------------------
// grid (bc, dquarter); block stages Bpre in LDS; wave = 4 m-tiles x 4 s-tiles.
__global__ __launch_bounds__(256) void scT_kernel(
    const unsigned short* __restrict__ Bpre, const unsigned short* __restrict__ xT,
    unsigned short* __restrict__ ScT) {
  __shared__ __align__(16) unsigned short Bprel[64][40];
  int tid = threadIdx.x;
  int bc = blockIdx.x;
  int dq = blockIdx.y;  // 0..3
  {
    int s = tid >> 2, c8 = (tid & 3) * 8;
    *(u16x8*)&Bprel[s][c8] = *(const u16x8*)(Bpre + (size_t)bc * 2048 + s * kQ + c8);
  }
  __syncthreads();
  int w = tid >> 6, lane = tid & 63;
  int l15 = lane & 15, lk = lane >> 4;
  bf16x8 bfr[4];
#pragma unroll
  for (int st = 0; st < 4; ++st)
    bfr[st] = *(const bf16x8*)&Bprel[st * 16 + l15][lk * 8];
  const unsigned short* xTb = xT + (size_t)bc * kD * kQ;
  unsigned short* so = ScT + (size_t)bc * kD * kS;
#pragma unroll
  for (int mt = 0; mt < 4; ++mt) {
    int d0t = dq * 256 + (w * 4 + mt) * 16;
    bf16x8 af = *(const bf16x8*)(xTb + (size_t)(d0t + l15) * kQ + lk * 8);
    f32x4 acc[4];
#pragma unroll
    for (int st = 0; st < 4; ++st) {
      f32x4 z = {0.f, 0.f, 0.f, 0.f};
      acc[st] = __builtin_amdgcn_mfma_f32_16x16x32_bf16(af, bfr[st], z, 0, 0, 0);
    }
#pragma unroll
    for (int st = 0; st < 4; ++st)
#pragma unroll
      for (int r = 0; r < 4; ++r)
        so[(size_t)(d0t + lk * 4 + r) * kS + st * 16 + l15] = f2bf_(acc[st][r]);
  }
}

// ---------------- K4: cross-chunk scan on ScT (flat, burst-prefetched) ----
__global__ __launch_bounds__(256) void chscan_kernel(
    const float* __restrict__ dec, unsigned short* __restrict__ Sc) {
  int bk = blockIdx.x >> 7;           // batch
  int part = blockIdx.x & 127;
  int p = part * 256 + threadIdx.x;   // pair index over kS*kD/2
  int flat = p * 2;                   // element index (d*64 + s), s0 even
  int s0 = flat & 63;
  const size_t cstride = (size_t)kS * kD;
  size_t base = (size_t)bk * kTC * cstride + flat;
  const float* decb = dec + (size_t)bk * kTC * kS + s0;
  float r0 = 0.f, r1 = 0.f;
  for (int c0 = 0; c0 < kTC; c0 += 16) {
    int n = kTC - c0;
    if (n > 16) n = 16;
    unsigned v[16];
    float2 dd[16];
#pragma unroll
    for (int j = 0; j < 16; ++j) {
      if (j < n) {
        v[j] = *(const unsigned*)(Sc + base + (size_t)(c0 + j) * cstride);
        dd[j] = *(const float2*)(decb + (size_t)(c0 + j) * kS);
      }
    }
#pragma unroll
    for (int j = 0; j < 16; ++j) {
      if (j < n) {
        unsigned ost = (unsigned)f2bf_(r0) | ((unsigned)f2bf_(r1) << 16);
        *(unsigned*)(Sc + base + (size_t)(c0 + j) * cstride) = ost;  // H_before
        r0 = fmaf(dd[j].x, r0, bf2f_((unsigned short)(v[j] & 0xFFFF)));
        r1 = fmaf(dd[j].y, r1, bf2f_((unsigned short)(v[j] >> 16)));
      }
    }
  }
}

// ---------------- K5: passB — y = G@x + C~@H0 + ds*x, all-MFMA ------------
// grid (bc, quarter); no LDS, no sync; wave = 64 d, 2 m-tiles (32 t).
__global__ __launch_bounds__(256) void passB_kernel(
    const unsigned short* __restrict__ Gm, const unsigned short* __restrict__ Ctb,
    const unsigned short* __restrict__ xT, const unsigned short* __restrict__ hT,
    const float* __restrict__ D_skip, float* __restrict__ out) {
  int tid = threadIdx.x;
  int bc = blockIdx.x;
  int quarter = blockIdx.y;
  int b = bc / kTC, c = bc % kTC;
  int t0c = c * kQ;
  int clen = min(kQ, kLc - t0c);
  int w = tid >> 6, lane = tid & 63;
  int l15 = lane & 15, lk = lane >> 4;

  const unsigned short* Gb = Gm + (size_t)bc * 32 * kQ;
  bf16x8 aG0 = *(const bf16x8*)(Gb + (size_t)l15 * kQ + lk * 8);
  bf16x8 aG1 = *(const bf16x8*)(Gb + (size_t)(16 + l15) * kQ + lk * 8);
  const unsigned short* Cb = Ctb + (size_t)bc * 2048;
  bf16x8 aC0l = *(const bf16x8*)(Cb + (size_t)l15 * kS + lk * 8);
  bf16x8 aC0h = *(const bf16x8*)(Cb + (size_t)l15 * kS + 32 + lk * 8);
  bf16x8 aC1l = *(const bf16x8*)(Cb + (size_t)(16 + l15) * kS + lk * 8);
  bf16x8 aC1h = *(const bf16x8*)(Cb + (size_t)(16 + l15) * kS + 32 + lk * 8);

  const unsigned short* xTb = xT + (size_t)bc * kD * kQ;
  const unsigned short* hTb = hT + (size_t)bc * kD * kS;
  size_t rowbase = (size_t)b * kLc + t0c;
  int dbase = quarter * 256 + w * 64;

#pragma unroll
  for (int nt = 0; nt < 4; ++nt) {
    int d = dbase + nt * 16 + l15;
    bf16x8 bX  = *(const bf16x8*)(xTb + (size_t)d * kQ + lk * 8);
    bf16x8 bHl = *(const bf16x8*)(hTb + (size_t)d * kS + lk * 8);
    bf16x8 bHh = *(const bf16x8*)(hTb + (size_t)d * kS + 32 + lk * 8);
    f32x4 z = {0.f, 0.f, 0.f, 0.f};
    f32x4 accA = __builtin_amdgcn_mfma_f32_16x16x32_bf16(aC0l, bHl, z, 0, 0, 0);
    accA = __builtin_amdgcn_mfma_f32_16x16x32_bf16(aC0h, bHh, accA, 0, 0, 0);
    accA = __builtin_amdgcn_mfma_f32_16x16x32_bf16(aG0, bX, accA, 0, 0, 0);
    f32x4 accB = __builtin_amdgcn_mfma_f32_16x16x32_bf16(aC1l, bHl, z, 0, 0, 0);
    accB = __builtin_amdgcn_mfma_f32_16x16x32_bf16(aC1h, bHh, accB, 0, 0, 0);
    accB = __builtin_amdgcn_mfma_f32_16x16x32_bf16(aG1, bX, accB, 0, 0, 0);

    float ds = D_skip[d];
    ushort4 xa = *(const ushort4*)(xTb + (size_t)d * kQ + lk * 4);
    ushort4 xb = *(const ushort4*)(xTb + (size_t)d * kQ + 16 + lk * 4);
    const unsigned short* xap = (const unsigned short*)&xa;
    const unsigned short* xbp = (const unsigned short*)&xb;
#pragma unroll
    for (int r = 0; r < 4; ++r) {
      int t = lk * 4 + r;
      if (t < clen)
        out[(rowbase + t) * kD + d] = fmaf(ds, bf2f_(xap[r]), accA[r]);
      int t2 = 16 + lk * 4 + r;
      if (t2 < clen)
        out[(rowbase + t2) * kD + d] = fmaf(ds, bf2f_(xbp[r]), accB[r]);
    }
  }
}

extern "C" void kernel_launch(void* const* d_in, const int* in_sizes, int n_in,
                              void* d_out, int out_size, void* d_ws, size_t ws_size,
                              hipStream_t stream) {
  const float* x      = (const float*)d_in[0];
  const float* a_hat  = (const float*)d_in[1];
  const float* W_U    = (const float*)d_in[2];
  const float* W_B    = (const float*)d_in[3];
  const float* b_B    = (const float*)d_in[4];
  const float* W_C    = (const float*)d_in[5];
  const float* b_C    = (const float*)d_in[6];
  const float* W_d1   = (const float*)d_in[7];
  const float* b_d1   = (const float*)d_in[8];
  const float* W_d2   = (const float*)d_in[9];
  const float* b_d2   = (const float*)d_in[10];
  const float* D_skip = (const float*)d_in[11];
  const float* conv_w = (const float*)d_in[12];
  const float* conv_b = (const float*)d_in[13];
  float* out = (float*)d_out;

  char* w = (char*)d_ws;
  auto nextp = [&](size_t bytes) {
    char* p = w;
    w += (bytes + 255) & ~(size_t)255;
    return p;
  };
  unsigned short* xcb  = (unsigned short*)nextp((size_t)kM * kD * 2);
  unsigned short* wcat = (unsigned short*)nextp((size_t)256 * kD * 2);
  unsigned short* xT   = (unsigned short*)nextp((size_t)kB * kTC * kD * kQ * 2);
  float*          raw  = (float*)nextp((size_t)kM * kNR * 4);
  unsigned short* Gm   = (unsigned short*)nextp((size_t)kB * kTC * 32 * kQ * 2);
  unsigned short* Ctb  = (unsigned short*)nextp((size_t)kB * kTC * 2048 * 2);
  unsigned short* Bpre = (unsigned short*)nextp((size_t)kB * kTC * 2048 * 2);
  float*          dec  = (float*)nextp((size_t)kB * kTC * kS * 4);
  unsigned short* ScT  = (unsigned short*)nextp((size_t)kB * kTC * kD * kS * 2);

  int convThreads = kB * kLc * (kD / 4);
  conv_kernel<<<(convThreads + 255) / 256, 256, 0, stream>>>(x, conv_w, conv_b, xcb);

  wcat_kernel<<<256, 256, 0, stream>>>(W_U, W_B, W_C, W_d1, wcat);

  dim3 xgrid(kB * kTC, kD / 128);
  xpose_kernel<<<xgrid, 256, 0, stream>>>(xcb, xT);

  dim3 ggrid((kM + 31) / 32, 2);
  gemm_mfma_kernel<<<ggrid, 256, 0, stream>>>(xcb, wcat, raw);

  passA_kernel<<<kB * kTC, 256, 0, stream>>>(
      raw, b_B, b_C, b_d1, W_d2, b_d2, a_hat, Gm, Ctb, Bpre, dec);

  dim3 sgrid(kB * kTC, 4);
  scT_kernel<<<sgrid, 256, 0, stream>>>(Bpre, xT, ScT);

  chscan_kernel<<<kB * 128, 256, 0, stream>>>(dec, ScT);

  dim3 bgrid(kB * kTC, 4);
  passB_kernel<<<bgrid, 256, 0, stream>>>(Gm, Ctb, xT, ScT, D_skip, out);
}